// Round 2
// baseline (476.532 us; speedup 1.0000x reference)
//
#include <hip/hip_runtime.h>
#include <cmath>

#define GN 2048
#define GB 16

typedef __attribute__((ext_vector_type(8))) short bf8_t;
typedef __attribute__((ext_vector_type(4))) float f4_t;

__device__ __forceinline__ short f2bf(float f) {
    union { float f; unsigned u; } v; v.f = f;
    unsigned r = v.u + 0x7FFFu + ((v.u >> 16) & 1u);
    return (short)(r >> 16);
}
__device__ __forceinline__ float bf2f(short s) {
    union { unsigned u; float f; } v; v.u = ((unsigned)(unsigned short)s) << 16;
    return v.f;
}

// async 16B/lane global->LDS (wave-uniform LDS base, lane i lands at base+i*16)
__device__ __forceinline__ void load16_lds(const short* g, short* l) {
    __builtin_amdgcn_global_load_lds(
        (const __attribute__((address_space(1))) unsigned int*)g,
        (__attribute__((address_space(3))) unsigned int*)l, 16, 0, 0);
}

// ---------------- reductions ----------------
__device__ __forceinline__ float wave_max(float v) {
#pragma unroll
    for (int o = 32; o > 0; o >>= 1) v = fmaxf(v, __shfl_xor(v, o, 64));
    return v;
}
__device__ __forceinline__ float wave_sum(float v) {
#pragma unroll
    for (int o = 32; o > 0; o >>= 1) v += __shfl_xor(v, o, 64);
    return v;
}
__device__ __forceinline__ float block_sum(float v) {
    __shared__ float sm[4];
    v = wave_sum(v);
    if ((threadIdx.x & 63) == 0) sm[threadIdx.x >> 6] = v;
    __syncthreads();
    v = sm[0] + sm[1] + sm[2] + sm[3];
    __syncthreads();
    return v;
}

// ---------------- fused fp32 -> bf16 weight convert (dst region contiguous) ----------------
__global__ __launch_bounds__(256) void f2ball_k(
    const float* __restrict__ w2, const float* __restrict__ w3,
    const float* __restrict__ wqk, const float* __restrict__ wv,
    const float* __restrict__ wt, const float* __restrict__ w4,
    short* __restrict__ dst) {
    int i = blockIdx.x * 256 + threadIdx.x;
    if (i >= 1409024) return;
    float v;
    if (i < 32768) v = w2[i];
    else if (i < 294912) v = w3[i - 32768];
    else if (i < 360448) v = wqk[i - 294912];
    else if (i < 622592) v = wv[i - 360448];
    else if (i < 884736) v = wt[i - 622592];
    else v = w4[i - 884736];
    dst[i] = f2bf(v);
}

// ---------------- posenc + conv1 + relu -> h1T [32768, 128] bf16 ----------------
__global__ __launch_bounds__(256) void posenc_conv1_k(
    const float* __restrict__ x, const float* __restrict__ w1,
    const float* __restrict__ b1, short* __restrict__ h1) {
    __shared__ float w[128 * 21];
    __shared__ float bb[128];
    __shared__ float se[256][21];
    const int tid = threadIdx.x;
    for (int i = tid; i < 128 * 21; i += 256) w[i] = w1[i];
    if (tid < 128) bb[tid] = b1[tid];
    int p0 = blockIdx.x * 256;
    int p = p0 + tid, b = p >> 11, n = p & (GN - 1);
    const float* xb = x + (long)b * 3 * GN + n;
    float t0 = xb[0], t1 = xb[GN], t2 = xb[2 * GN];
    se[tid][0] = t0; se[tid][1] = t1; se[tid][2] = t2;
    se[tid][3] = sinf(t0); se[tid][4] = sinf(t1); se[tid][5] = sinf(t2);
    se[tid][6] = cosf(t0); se[tid][7] = cosf(t1); se[tid][8] = cosf(t2);
    se[tid][9] = sinf(2.f * t0); se[tid][10] = sinf(2.f * t1); se[tid][11] = sinf(2.f * t2);
    se[tid][12] = cosf(2.f * t0); se[tid][13] = cosf(2.f * t1); se[tid][14] = cosf(2.f * t2);
    se[tid][15] = sinf(4.f * t0); se[tid][16] = sinf(4.f * t1); se[tid][17] = sinf(4.f * t2);
    se[tid][18] = cosf(4.f * t0); se[tid][19] = cosf(4.f * t1); se[tid][20] = cosf(4.f * t2);
    __syncthreads();
    short* outb = h1 + (long)p0 * 128;
    for (int it = 0; it < 128; ++it) {
        int L = it * 256 + tid;
        int pl = L >> 7, o = L & 127;
        float s = bb[o];
        const float* er = se[pl];
        const float* wr = &w[o * 21];
#pragma unroll
        for (int c = 0; c < 21; ++c) s = fmaf(wr[c], er[c], s);
        outb[L] = f2bf(fmaxf(s, 0.f));
    }
}

// ---------------- MFMA GEMM: D[row,col] = sum_k A[row,k]*B[col,k] ----------------
// R14 engine: 256 threads, 128x128 block tile, BK=64, single-buffered LDS via
// global_load_lds, 2-barrier loop with explicit vmcnt(0) drain. Kept for the
// small/odd-shaped GEMMs (steps 2, 6, 8a).
template <int MODE, int BIAS, bool RELU, bool STATS = false, bool COLMAX = false>
__global__ __launch_bounds__(256) void mm_k(
    const short* __restrict__ A, int lda, long long aB,
    const short* __restrict__ B, int ldb, long long bB,
    const float* __restrict__ bias, int biasStride,
    const short* __restrict__ aux, long long auxB,
    const float* __restrict__ rsv,
    float* __restrict__ Cf, long long cfB,
    short* __restrict__ Cb, long long cbB,
    float* __restrict__ Pmax, float* __restrict__ Ps2,
    int ldc, int K) {
    const int z = blockIdx.z;
    A += (long long)z * aB;
    B += (long long)z * bB;
    if (MODE == 4) { aux += (long long)z * auxB; rsv += (long long)z * GN; }
    if (MODE == 1) Cf += (long long)z * cfB;
    if (MODE == 2 || MODE == 4 || MODE == 6) Cb += (long long)z * cbB;
    if (MODE == 6) Pmax += (long long)z * GN * 32;
    const int row0 = blockIdx.x * 128, col0 = blockIdx.y * 128;
    const int tid = threadIdx.x;
    const int lane = tid & 63, w = tid >> 6;
    const int r = lane & 15, q = lane >> 4;
    const int wr = w >> 1, wc = w & 1;

    __shared__ short lA[8192];
    __shared__ short lB[8192];

    f4_t acc[4][4] = {};

    const int sRow = lane >> 2;
    const int sKb = (lane & 3) ^ ((lane >> 3) & 3);
    const long aG = (long)(row0 + w * 32 + sRow) * lda + sKb * 8;
    const long bG = (long)(col0 + w * 32 + sRow) * ldb + sKb * 8;
    short* ldsA0 = lA + (w * 32) * 32;
    short* ldsA1 = lA + (w * 32 + 16) * 32;
    short* ldsB0 = lB + (w * 32) * 32;
    short* ldsB1 = lB + (w * 32 + 16) * 32;

    const int sw = (q ^ ((r >> 1) & 3)) * 8;
    int aoff[4], boff[4];
#pragma unroll
    for (int i = 0; i < 4; ++i) {
        aoff[i] = (wr * 64 + i * 16 + r) * 32 + sw;
        boff[i] = (wc * 64 + i * 16 + r) * 32 + sw;
    }

    for (int k0 = 0; k0 < K; k0 += 64) {
        __syncthreads();
        load16_lds(A + aG + k0, ldsA0);
        load16_lds(A + aG + (long)16 * lda + k0, ldsA1);
        load16_lds(B + bG + k0, ldsB0);
        load16_lds(B + bG + (long)16 * ldb + k0, ldsB1);
        load16_lds(A + aG + k0 + 32, ldsA0 + 4096);
        load16_lds(A + aG + (long)16 * lda + k0 + 32, ldsA1 + 4096);
        load16_lds(B + bG + k0 + 32, ldsB0 + 4096);
        load16_lds(B + bG + (long)16 * ldb + k0 + 32, ldsB1 + 4096);
        asm volatile("s_waitcnt vmcnt(0)" ::: "memory");
        __syncthreads();
#pragma unroll
        for (int h = 0; h < 2; ++h) {
            const short* la = lA + h * 4096;
            const short* lb = lB + h * 4096;
            bf8_t av[4], bv[4];
#pragma unroll
            for (int i = 0; i < 4; ++i) av[i] = *(const bf8_t*)(la + aoff[i]);
#pragma unroll
            for (int j = 0; j < 4; ++j) bv[j] = *(const bf8_t*)(lb + boff[j]);
#pragma unroll
            for (int i = 0; i < 4; ++i)
#pragma unroll
                for (int j = 0; j < 4; ++j)
                    acc[i][j] = __builtin_amdgcn_mfma_f32_16x16x32_bf16(av[i], bv[j], acc[i][j], 0, 0, 0);
        }
    }

    if constexpr (MODE == 5) {
        int b = row0 >> 11;
        int rw = (blockIdx.x * 2 + wr) & 31;
#pragma unroll
        for (int j = 0; j < 4; ++j) {
            float vm = -1e30f;
#pragma unroll
            for (int i = 0; i < 4; ++i)
#pragma unroll
                for (int e = 0; e < 4; ++e) vm = fmaxf(vm, acc[i][j][e]);
            vm = fmaxf(vm, __shfl_xor(vm, 16, 64));
            vm = fmaxf(vm, __shfl_xor(vm, 32, 64));
            if (q == 0) {
                int gcol = col0 + wc * 64 + j * 16 + r;
                Pmax[(((long)b * 1024 + gcol) << 5) + rw] = vm + bias[gcol];
            }
        }
    } else if constexpr (MODE == 6) {
        float rsum[4][4] = {};
#pragma unroll
        for (int j = 0; j < 4; ++j) {
            int gcol = col0 + wc * 64 + j * 16 + r;
#pragma unroll
            for (int i = 0; i < 4; ++i) {
#pragma unroll
                for (int e = 0; e < 4; ++e) {
                    int grow = row0 + wr * 64 + i * 16 + q * 4 + e;
                    float ex = __expf(acc[i][j][e]);
                    rsum[i][e] += ex;
                    Cb[(long)grow * ldc + gcol] = f2bf(ex);
                }
            }
        }
#pragma unroll
        for (int i = 0; i < 4; ++i)
#pragma unroll
            for (int e = 0; e < 4; ++e) {
                float v = rsum[i][e];
                v += __shfl_xor(v, 1, 64);
                v += __shfl_xor(v, 2, 64);
                v += __shfl_xor(v, 4, 64);
                v += __shfl_xor(v, 8, 64);
                if (r == 0) {
                    int grow = row0 + wr * 64 + i * 16 + q * 4 + e;
                    Pmax[((long)grow << 5) + blockIdx.y * 2 + wc] = v;
                }
            }
    } else if constexpr (MODE == 4) {
#pragma unroll
        for (int i = 0; i < 4; ++i) {
#pragma unroll
            for (int e = 0; e < 4; ++e) {
                int grow = row0 + wr * 64 + i * 16 + q * 4 + e;
                float rsr = rsv[grow];
                long ob = (long)grow * ldc + col0 + wc * 64 + r;
#pragma unroll
                for (int j = 0; j < 4; ++j) {
                    long off = ob + j * 16;
                    Cb[off] = f2bf(bf2f(aux[off]) - acc[i][j][e] * rsr);
                }
            }
        }
    } else {
        const int b2d = (BIAS == 3) ? (row0 >> 11) : 0;
#pragma unroll
        for (int j = 0; j < 4; ++j) {
            int gcol = col0 + wc * 64 + j * 16 + r;
            float bvv = 0.f;
            if constexpr (BIAS == 1) bvv = bias[gcol];
            if constexpr (BIAS == 3) bvv = bias[b2d * biasStride + gcol];
            float s1 = 0.f, s2 = 0.f;
            float cmx = -1e30f;
#pragma unroll
            for (int i = 0; i < 4; ++i) {
#pragma unroll
                for (int e = 0; e < 4; ++e) {
                    int grow = row0 + wr * 64 + i * 16 + q * 4 + e;
                    float v = acc[i][j][e] + bvv;
                    if constexpr (BIAS == 2) v += bias[grow];
                    if constexpr (RELU) v = fmaxf(v, 0.f);
                    if constexpr (STATS) { s1 += v; s2 = fmaf(v, v, s2); }
                    if constexpr (COLMAX) cmx = fmaxf(cmx, v);
                    long off = (long)grow * ldc + gcol;
                    if constexpr (MODE == 1) Cf[off] = v;
                    if constexpr (MODE == 2) Cb[off] = f2bf(v);
                }
            }
            if constexpr (STATS) {
                s1 += __shfl_xor(s1, 16, 64); s1 += __shfl_xor(s1, 32, 64);
                s2 += __shfl_xor(s2, 16, 64); s2 += __shfl_xor(s2, 32, 64);
                if (q == 0) {
                    int rw2 = blockIdx.x * 2 + wr;
                    Pmax[rw2 * 512 + gcol] = s1;
                    Ps2[rw2 * 512 + gcol] = s2;
                }
            }
            if constexpr (COLMAX) {
                cmx = fmaxf(cmx, __shfl_xor(cmx, 16, 64));
                cmx = fmaxf(cmx, __shfl_xor(cmx, 32, 64));
                if (q == 0) {
                    int b = row0 >> 11;
                    int rw = (blockIdx.x * 2 + wr) & 31;
                    Pmax[(((long)b * ldc + gcol) << 5) + rw] = cmx;
                }
            }
        }
    }
}

// ================= 256x256 deep-pipelined MFMA GEMM engine (T2+T3+T4+T5) ======
// (see R1 comments; unchanged core schedule). NEW this round:
//  - SWZ template param: chunked XCD swizzle (m204 bijective form, requires
//    nwg%8==0) so work items sharing A-row-panels land on the same XCD L2.
//  - BIAS==2 (per-row bias) and BIAS==3 (per-batch col bias, biasStride) in
//    the MODE 2 epilogue (enables steps 5 & 7 migration).
__device__ __forceinline__ void stage2(const short* g0, const short* g1, short* dst) {
    load16_lds(g0, dst);
    load16_lds(g1, dst + 4096);
}

template <int MH, int NH>
__device__ __forceinline__ void mfma_quad(const bf8_t (&av)[4][2], const bf8_t (&bv)[2][2],
                                          f4_t (&acc)[8][4]) {
#pragma unroll
    for (int mi = 0; mi < 4; ++mi)
#pragma unroll
        for (int ni = 0; ni < 2; ++ni) {
            acc[MH * 4 + mi][NH * 2 + ni] = __builtin_amdgcn_mfma_f32_16x16x32_bf16(
                av[mi][0], bv[ni][0], acc[MH * 4 + mi][NH * 2 + ni], 0, 0, 0);
            acc[MH * 4 + mi][NH * 2 + ni] = __builtin_amdgcn_mfma_f32_16x16x32_bf16(
                av[mi][1], bv[ni][1], acc[MH * 4 + mi][NH * 2 + ni], 0, 0, 0);
        }
}

__device__ __forceinline__ void rd4(const short* p, int swz0, int swz1, bf8_t (&v)[4][2]) {
#pragma unroll
    for (int i = 0; i < 4; ++i) {
        v[i][0] = *(const bf8_t*)(p + i * 1024 + swz0);
        v[i][1] = *(const bf8_t*)(p + i * 1024 + swz1);
    }
}
__device__ __forceinline__ void rd2(const short* p, int swz0, int swz1, bf8_t (&v)[2][2]) {
#pragma unroll
    for (int i = 0; i < 2; ++i) {
        v[i][0] = *(const bf8_t*)(p + i * 1024 + swz0);
        v[i][1] = *(const bf8_t*)(p + i * 1024 + swz1);
    }
}

#define SB0 __builtin_amdgcn_sched_barrier(0)
#define BARRIER asm volatile("s_barrier" ::: "memory")

// MODE: 2=Cb=bf16(D+bias) [opt STATS], 4=Cb=bf16(aux - rs[row]*D), 5=col-max partials
template <int MODE, int BIAS, bool RELU, bool STATS = false, bool SWZ = false>
__global__ __launch_bounds__(512, 2) void mm256_k(
    const short* __restrict__ A, int lda, long long aB,
    const short* __restrict__ B, int ldb, long long bB,
    const float* __restrict__ bias, int biasStride,
    const short* __restrict__ aux, long long auxB,
    const float* __restrict__ rsv,
    short* __restrict__ Cb, long long cbB,
    float* __restrict__ Pmax, float* __restrict__ Ps2,
    int ldc, int K) {
    __shared__ short lA[32768];
    __shared__ short lB[32768];
    // ---- block index (optionally XCD-chunk-swizzled; nwg must be %8==0) ----
    int bx = blockIdx.x, by = blockIdx.y, bz = blockIdx.z;
    if constexpr (SWZ) {
        const int nwg = gridDim.x * gridDim.y * gridDim.z;
        const int bid = bx + gridDim.x * (by + gridDim.y * bz);
        const int cpx = nwg >> 3;
        const int wg = (bid & 7) * cpx + (bid >> 3);
        bx = wg % gridDim.x;
        const int t2 = wg / gridDim.x;
        by = t2 % gridDim.y;
        bz = t2 / gridDim.y;
    }
    const int z = bz;
    A += (long long)z * aB;
    B += (long long)z * bB;
    if constexpr (MODE == 4) { aux += (long long)z * auxB; rsv += (long long)z * GN; }
    if constexpr (MODE != 5) Cb += (long long)z * cbB;
    const int row0 = bx * 256, col0 = by * 256;
    const int tid = threadIdx.x;
    const int lane = tid & 63, w = tid >> 6;
    const int r16 = lane & 15, q = lane >> 4;
    const int wr = w >> 2, wc = w & 3;

    // ---- staging sources (pre-swizzled k-slot so linear LDS dest => swizzled layout)
    const int rc0 = w * 8 + (lane >> 3);            // row-in-half, call0 (call1 = +64)
    const int s8 = ((lane & 7) ^ (rc0 & 7)) * 8;    // swizzled 16B k-slot (shorts)
    const long ldA64 = (long)64 * lda, ldB64 = (long)64 * ldb;
    const short* aH0 = A + (long)(row0 + rc0) * lda + s8;
    const short* aH1 = aH0 + (long)128 * lda;
    const short* bH0 = B + (long)(col0 + rc0) * ldb + s8;
    const short* bH1 = bH0 + (long)128 * ldb;
    short* dA = lA + w * 512;   // wave-uniform LDS chunk base (1 KB/wave/call)
    short* dB = lB + w * 512;

#define STG_A(d_, h_, kt_) stage2((h_ ? aH1 : aH0) + (long)(kt_) * 64,                      \
                                  (h_ ? aH1 : aH0) + (long)(kt_) * 64 + ldA64,              \
                                  dA + (d_) * 16384 + (h_) * 8192)
#define STG_B(d_, h_, kt_) stage2((h_ ? bH1 : bH0) + (long)(kt_) * 64,                      \
                                  (h_ ? bH1 : bH0) + (long)(kt_) * 64 + ldB64,              \
                                  dB + (d_) * 16384 + (h_) * 8192)

    // ---- fragment read offsets (swizzle XOR depends only on r16&7)
    const int swz0 = (q ^ (r16 & 7)) * 8;         // ks=0
    const int swz1 = ((4 + q) ^ (r16 & 7)) * 8;   // ks=1
    const int arow = (wr * 64 + r16) * 64;
    const int brow = (wc * 32 + r16) * 64;

    f4_t acc[8][4] = {};
    bf8_t av[4][2], bv0[2][2], bv1[2][2];
    const int NT = K >> 6;

    // ---- prologue: tile0 (Ah0,Bh0,Bh1,Ah1) + tile1 (Ah0,Bh0) = 12 loads/wave
    STG_A(0, 0, 0); STG_B(0, 0, 0); STG_B(0, 1, 0); STG_A(0, 1, 0);
    STG_A(1, 0, 1); STG_B(1, 0, 1);
    asm volatile("s_waitcnt vmcnt(4)" ::: "memory");  // tile0 landed, 2 halves in flight
    SB0; BARRIER; SB0;

    for (int t = 0; t < NT; ++t) {
        const int d = t & 1;
        const short* la = lA + d * 16384;
        const short* lb = lB + d * 16384;
        // phase 1: quadrant (0,0); stage Bh1(t+1)
        rd4(la + arow, swz0, swz1, av);
        rd2(lb + brow, swz0, swz1, bv0);
        if (t + 1 < NT) STG_B(d ^ 1, 1, t + 1);
        SB0; BARRIER; SB0;
        __builtin_amdgcn_s_setprio(1);
        mfma_quad<0, 0>(av, bv0, acc);
        __builtin_amdgcn_s_setprio(0);
        SB0; BARRIER; SB0;
        // phase 2: quadrant (0,1); stage Ah1(t+1)   [A-regs reused]
        rd2(lb + 8192 + brow, swz0, swz1, bv1);
        if (t + 1 < NT) STG_A(d ^ 1, 1, t + 1);
        SB0; BARRIER; SB0;
        __builtin_amdgcn_s_setprio(1);
        mfma_quad<0, 1>(av, bv1, acc);
        __builtin_amdgcn_s_setprio(0);
        SB0; BARRIER; SB0;
        // phase 3: quadrant (1,0); stage Ah0(t+2) into current buf (Ah0 last read ph1)
        rd4(la + 8192 + arow, swz0, swz1, av);
        if (t + 2 < NT) STG_A(d, 0, t + 2);
        SB0; BARRIER; SB0;
        __builtin_amdgcn_s_setprio(1);
        mfma_quad<1, 0>(av, bv0, acc);
        __builtin_amdgcn_s_setprio(0);
        SB0; BARRIER; SB0;
        // phase 4: quadrant (1,1); stage Bh0(t+2) (Bh0 last read ph3); counted vmcnt
        if (t + 2 < NT) {
            STG_B(d, 0, t + 2);
            asm volatile("s_waitcnt vmcnt(4)" ::: "memory");  // tile t+1 landed, 2 in flight
        } else if (t + 1 < NT) {
            asm volatile("s_waitcnt vmcnt(0)" ::: "memory");  // drain for final tile
        }
        SB0; BARRIER; SB0;
        __builtin_amdgcn_s_setprio(1);
        mfma_quad<1, 1>(av, bv1, acc);
        __builtin_amdgcn_s_setprio(0);
        SB0; BARRIER; SB0;
    }
#undef STG_A
#undef STG_B

    // ---- epilogues ----
    const int mrow = row0 + wr * 64 + q * 4;   // + mh*128 + mi*16 + e
    const int ncol = col0 + wc * 32 + r16;     // + nh*128 + ni*16

    if constexpr (MODE == 4) {
#pragma unroll
        for (int m = 0; m < 8; ++m) {
#pragma unroll
            for (int e = 0; e < 4; ++e) {
                const int grow = mrow + (m >> 2) * 128 + (m & 3) * 16 + e;
                const float rsr = rsv[grow];
                const long rb = (long)grow * ldc;
#pragma unroll
                for (int n = 0; n < 4; ++n) {
                    const long off = rb + ncol + (n >> 1) * 128 + (n & 1) * 16;
                    Cb[off] = f2bf(bf2f(aux[off]) - acc[m][n][e] * rsr);
                }
            }
        }
    } else if constexpr (MODE == 2) {
        const int b2d = (BIAS == 3) ? (row0 >> 11) : 0;
#pragma unroll
        for (int n = 0; n < 4; ++n) {
            const int gcol = ncol + (n >> 1) * 128 + (n & 1) * 16;
            float bvv = 0.f;
            if constexpr (BIAS == 1) bvv = bias[gcol];
            if constexpr (BIAS == 3) bvv = bias[b2d * biasStride + gcol];
#pragma unroll
            for (int mh = 0; mh < 2; ++mh) {
                float s1 = 0.f, s2 = 0.f;
#pragma unroll
                for (int mi = 0; mi < 4; ++mi) {
#pragma unroll
                    for (int e = 0; e < 4; ++e) {
                        const int grow = mrow + mh * 128 + mi * 16 + e;
                        float v = acc[mh * 4 + mi][n][e] + bvv;
                        if constexpr (BIAS == 2) v += bias[grow];
                        if constexpr (RELU) v = fmaxf(v, 0.f);
                        if constexpr (STATS) { s1 += v; s2 = fmaf(v, v, s2); }
                        Cb[(long)grow * ldc + gcol] = f2bf(v);
                    }
                }
                if constexpr (STATS) {
                    s1 += __shfl_xor(s1, 16, 64); s1 += __shfl_xor(s1, 32, 64);
                    s2 += __shfl_xor(s2, 16, 64); s2 += __shfl_xor(s2, 32, 64);
                    if (q == 0) {
                        const int rw2 = bx * 4 + mh * 2 + wr;  // 64-row group
                        Pmax[rw2 * 512 + gcol] = s1;
                        Ps2[rw2 * 512 + gcol] = s2;
                    }
                }
            }
        }
    } else if constexpr (MODE == 5) {
        const int b = row0 >> 11;
#pragma unroll
        for (int n = 0; n < 4; ++n) {
            const int gcol = ncol + (n >> 1) * 128 + (n & 1) * 16;
            const float bvv = bias[gcol];
#pragma unroll
            for (int mh = 0; mh < 2; ++mh) {
                float vm = -1e30f;
#pragma unroll
                for (int mi = 0; mi < 4; ++mi)
#pragma unroll
                    for (int e = 0; e < 4; ++e) vm = fmaxf(vm, acc[mh * 4 + mi][n][e]);
                vm = fmaxf(vm, __shfl_xor(vm, 16, 64));
                vm = fmaxf(vm, __shfl_xor(vm, 32, 64));
                if (q == 0) {
                    const int rw = (bx * 4 + mh * 2 + wr) & 31;
                    Pmax[(((long)b * ldc + gcol) << 5) + rw] = vm + bvv;
                }
            }
        }
    }
}
#undef SB0
#undef BARRIER

// ---------------- rs[q] = 1 / sum of 32 row partials ----------------
__global__ __launch_bounds__(256) void rs_k(const float* __restrict__ rp,
                                            float* __restrict__ rs) {
    int i = blockIdx.x * 256 + threadIdx.x;
    const float* p = rp + ((long)i << 5);
    float s = 0.f;
#pragma unroll
    for (int j = 0; j < 32; ++j) s += p[j];
    rs[i] = 1.f / s;
}

// ---------------- g[i] = max over 32 partials ----------------
__global__ __launch_bounds__(256) void maxg_k(const float* __restrict__ P,
                                              float* __restrict__ g) {
    int i = blockIdx.x * 256 + threadIdx.x;
    const float* p = P + ((long)i << 5);
    float m = p[0];
#pragma unroll
    for (int j = 1; j < 32; ++j) m = fmaxf(m, p[j]);
    g[i] = m;
}

// ---------------- cvec[b,o] = b3[o] + sum_c w3[o,256+c]*g[b,c] (fp32) ----------------
__global__ __launch_bounds__(256) void cvec_k(const float* __restrict__ w3,
                                              const float* __restrict__ b3,
                                              const float* __restrict__ g,
                                              float* __restrict__ cvec) {
    int idx = blockIdx.x * 256 + threadIdx.x;
    int b = idx >> 9, o = idx & 511;
    const float* gb = g + (b << 8);
    const float* wr = w3 + (long)o * 512 + 256;
    float s = b3[o];
    for (int c = 0; c < 256; ++c) s = fmaf(wr[c], gb[c], s);
    cvec[idx] = s;
}

// ---------------- column sums of attn = P * rs[q] over q (two-stage) ----------------
// vectorized: 16B/lane coalesced reads, 8 columns per thread
__global__ __launch_bounds__(256) void colsum1_k(const short* __restrict__ Ab,
                                                 const float* __restrict__ rs,
                                                 float* __restrict__ cp) {
    const int qs = blockIdx.x, z = blockIdx.y;
    const int k0 = threadIdx.x * 8;
    const short* p = Ab + (long)z * GN * GN + (long)qs * 64 * GN + k0;
    const float* rv = rs + z * GN + qs * 64;
    float s[8] = {};
    for (int qq = 0; qq < 64; ++qq) {
        uint4 v = *(const uint4*)(p + (long)qq * GN);
        const float rr = rv[qq];
        const short* sp = (const short*)&v;
#pragma unroll
        for (int j = 0; j < 8; ++j) s[j] = fmaf(bf2f(sp[j]), rr, s[j]);
    }
    float* o = cp + ((long)(z * 32 + qs) * GN) + k0;
#pragma unroll
    for (int j = 0; j < 8; ++j) o[j] = s[j];
}
__global__ __launch_bounds__(256) void colsum2_k(const float* __restrict__ cp,
                                                 float* __restrict__ cs) {
    int k = blockIdx.x * 256 + threadIdx.x, z = blockIdx.y;
    float s = 1e-9f;
    for (int qs = 0; qs < 32; ++qs) s += cp[((z * 32 + qs) * GN) + k];
    cs[z * GN + k] = s;
}

// ---------------- xvc[c,p] /= cs[p]  (in place) ----------------
__global__ __launch_bounds__(256) void xvscale_k(short* __restrict__ xvc,
                                                 const float* __restrict__ cs) {
    long idx = ((long)blockIdx.x * 256 + threadIdx.x) * 4;
    int p = (int)(idx & 32767);
    short* ptr = xvc + idx;
    float4 cv = *(const float4*)(cs + p);
    uint2 u = *(const uint2*)ptr;
    short* sp = (short*)&u;
    sp[0] = f2bf(bf2f(sp[0]) / cv.x);
    sp[1] = f2bf(bf2f(sp[1]) / cv.y);
    sp[2] = f2bf(bf2f(sp[2]) / cv.z);
    sp[3] = f2bf(bf2f(sp[3]) / cv.w);
    *(uint2*)ptr = u;
}

// ---------------- BN scale/shift from fused GEMM stats [512][512] ----------------
__global__ __launch_bounds__(256) void bn2_k(const float* __restrict__ bs1,
                                             const float* __restrict__ bs2,
                                             const float* __restrict__ gamma,
                                             const float* __restrict__ beta,
                                             float* __restrict__ sc,
                                             float* __restrict__ sh) {
    int c = blockIdx.x;
    float s = 0.f, s2 = 0.f;
    for (int i = threadIdx.x; i < 512; i += 256) {
        s += bs1[i * 512 + c];
        s2 += bs2[i * 512 + c];
    }
    s = block_sum(s);
    s2 = block_sum(s2);
    if (threadIdx.x == 0) {
        const float cnt = (float)(GB * GN);
        float mu = s / cnt;
        float var = s2 / cnt - mu * mu;
        float r = rsqrtf(var + 1e-5f);
        float gm = gamma[c] * r;
        sc[c] = gm;
        sh[c] = beta[c] - gm * mu;
    }
}

// ---------------- h4T = bf16(h3b + relu(d*sc+sh)) ----------------
__global__ __launch_bounds__(256) void bn_apply_k(const short* __restrict__ h3b,
                                                  const short* __restrict__ d,
                                                  const float* __restrict__ sc,
                                                  const float* __restrict__ sh,
                                                  short* __restrict__ h4) {
    long bidx = ((long)blockIdx.x * 256 + threadIdx.x) * 4;
    int c = (int)(bidx & 511);
    uint2 du = *(const uint2*)(d + bidx);
    short* ds = (short*)&du;
    uint2 hu = *(const uint2*)(h3b + bidx);
    short* hs = (short*)&hu;
    float4 a4 = *(const float4*)(sc + c);
    float4 b4 = *(const float4*)(sh + c);
    float r0 = bf2f(hs[0]) + fmaxf(fmaf(bf2f(ds[0]), a4.x, b4.x), 0.f);
    float r1 = bf2f(hs[1]) + fmaxf(fmaf(bf2f(ds[1]), a4.y, b4.y), 0.f);
    float r2 = bf2f(hs[2]) + fmaxf(fmaf(bf2f(ds[2]), a4.z, b4.z), 0.f);
    float r3 = bf2f(hs[3]) + fmaxf(fmaf(bf2f(ds[3]), a4.w, b4.w), 0.f);
    uint2 o;
    o.x = (unsigned short)f2bf(r0) | ((unsigned)(unsigned short)f2bf(r1) << 16);
    o.y = (unsigned short)f2bf(r2) | ((unsigned)(unsigned short)f2bf(r3) << 16);
    *(uint2*)(h4 + bidx) = o;
}

// ---------------- out[i] = max over 32 partials ----------------
__global__ __launch_bounds__(256) void max_final_k(const float* __restrict__ P,
                                                   float* __restrict__ out) {
    int i = blockIdx.x * 256 + threadIdx.x;
    const float* p = P + ((long)i << 5);
    float m = p[0];
#pragma unroll
    for (int j = 1; j < 32; ++j) m = fmaxf(m, p[j]);
    out[i] = m;
}

extern "C" void kernel_launch(void* const* d_in, const int* in_sizes, int n_in,
                              void* d_out, int out_size, void* d_ws, size_t ws_size,
                              hipStream_t stream) {
    const float* x = (const float*)d_in[0];
    const float* w1 = (const float*)d_in[1];
    const float* b1 = (const float*)d_in[2];
    const float* w2 = (const float*)d_in[3];
    const float* b2 = (const float*)d_in[4];
    const float* w3 = (const float*)d_in[5];
    const float* b3 = (const float*)d_in[6];
    const float* w4 = (const float*)d_in[7];
    const float* b4 = (const float*)d_in[8];
    const float* wqk = (const float*)d_in[9];
    const float* wv = (const float*)d_in[10];
    const float* bv = (const float*)d_in[11];
    const float* wt = (const float*)d_in[12];
    const float* bt = (const float*)d_in[13];
    const float* gamma = (const float*)d_in[14];
    const float* beta = (const float*)d_in[15];
    float* out = (float*)d_out;

    // ---- workspace carve (bytes), peak ~255.05 MB (unchanged) ----
    char* base = (char*)d_ws;
    short* h3b = (short*)base;                    // [32768,512] bf16 32 MB
    short* hsT = (short*)(base + 33554432);       // [32768,512] bf16 32 MB
    short* kT  = (short*)(base + 67108864);       // [32768,128] bf16  8 MB
    short* xvc = (short*)(base + 75497472);       // [512,32768] bf16 32 MB (channel-major)
    short* EA  = (short*)(base + 109051904);      // [16,2048,2048] bf16 128 MB (P = exp(E))
    short* h1T = (short*)(base + 109051904);      //   alias (early, dead before EA)
    short* h2T = (short*)(base + 117440512);      //   alias (early)
    short* dTb = (short*)(base + 109051904);      //   alias [32768,512] bf16 (late, EA dead)
    short* h4T = (short*)(base + 67108864);       //   alias 32 MB over kT+xvc (late)
    char* S = base + 243269632;
    float* g    = (float*)(S + 262144);           // 16384
    float* cvec = (float*)(S + 278528);           // 32768
    float* cp   = (float*)(S + 311296);           // 4 MB [16,32,2048]; rp aliases (earlier)
    float* rp   = cp;                             //   [32768,32] row-sum partials
    float* cs   = (float*)(S + 4505600);          // 128 KB [16,2048]
    float* bs1  = (float*)(S + 4636672);          // 1 MB [512,512] fused BN sum partials
    float* bs2  = (float*)(S + 5685248);          // 1 MB [512,512] fused BN sumsq partials
    float* bnsc = (float*)(S + 6733824);          // 2048
    float* bnsh = (float*)(S + 6735872);          // 2048
    float* Pmax = (float*)(S + 6737920);          // 2 MB partials
    short* w2b  = (short*)(S + 8835072);          // bf16 weights, CONTIGUOUS region
    short* w3b  = (short*)(S + 8900608);
    short* wqkb = (short*)(S + 9424896);
    short* wvb  = (short*)(S + 9555968);
    short* wtb  = (short*)(S + 10080256);
    short* w4b  = (short*)(S + 10604544);
    float* rs   = (float*)(S + 11653120);         // 128 KB [16,2048] 1/rowsum

    // 0. all weight converts in one kernel
    f2ball_k<<<5505, 256, 0, stream>>>(w2, w3, wqk, wv, wt, w4, w2b);

    // 1. posenc + conv1 + relu -> h1T
    posenc_conv1_k<<<128, 256, 0, stream>>>(x, w1, b1, h1T);

    // 2. h2T = h1T @ w2^T + b2 + fused per-batch col-max partials (old engine)
    mm_k<2, 1, false, false, true><<<dim3(256, 2, 1), 256, 0, stream>>>(
        h1T, 128, 0, w2b, 128, 0, b2, 0, nullptr, 0, nullptr,
        nullptr, 0, h2T, 0, Pmax, nullptr, 256, 128);

    // 3. g[b,c] = max over 32 partials
    maxg_k<<<16, 256, 0, stream>>>(Pmax, g);

    // 4. cvec = w3[:,256:] @ g + b3 (fp32)
    cvec_k<<<32, 256, 0, stream>>>(w3, b3, g, cvec);

    // 5. h3b = bf16(relu(h2T @ w3[:,:256]^T + cvec))  [NEW engine, BIAS=3]
    mm256_k<2, 3, true><<<dim3(128, 2, 1), 512, 0, stream>>>(
        h2T, 256, 0, w3b, 512, 0, cvec, 512, nullptr, 0, nullptr,
        h3b, 0, nullptr, nullptr, 512, 256);

    // 6. kT = h3b @ wqk^T (cols=128 < 256: old engine)
    mm_k<2, 0, false><<<dim3(256, 1, 1), 256, 0, stream>>>(
        h3b, 512, 0, wqkb, 512, 0, nullptr, 0, nullptr, 0, nullptr,
        nullptr, 0, kT, 0, nullptr, nullptr, 128, 512);

    // 7. xv channel-major: D[c, point] = wv @ h3 + bv(row)  [NEW engine, BIAS=2]
    mm256_k<2, 2, false><<<dim3(2, 128, 1), 512, 0, stream>>>(
        wvb, 512, 0, h3b, 512, 0, bv, 0, nullptr, 0, nullptr,
        xvc, 0, nullptr, nullptr, 32768, 512);

    // 8a. P = exp(kT kT^T) bf16 + row-sum partials rp (old engine)
    mm_k<6, 0, false><<<dim3(16, 16, 16), 256, 0, stream>>>(
        kT, 128, (long long)GN * 128, kT, 128, (long long)GN * 128,
        nullptr, 0, nullptr, 0, nullptr, nullptr, 0,
        EA, (long long)GN * GN, rp, nullptr, GN, 128);
    // 8b. rs = 1/rowsum
    rs_k<<<128, 256, 0, stream>>>(rp, rs);
    // 8c. column sums of attn = P*rs (vectorized)
    colsum1_k<<<dim3(32, GB), 256, 0, stream>>>(EA, rs, cp);
    colsum2_k<<<dim3(8, GB), 256, 0, stream>>>(cp, cs);
    // 8d. fold L1 renorm into xv (in place)
    xvscale_k<<<16384, 256, 0, stream>>>(xvc, cs);
    // 8e. hsT = bf16(h3b - rs[q] * (P @ xv'^T))  [NEW engine + XCD swizzle]
    mm256_k<4, 0, false, false, true><<<dim3(8, 2, 16), 512, 0, stream>>>(
        EA, GN, (long long)GN * GN,
        xvc, 32768, (long long)GN,
        nullptr, 0, h3b, (long long)GN * 512, rs,
        hsT, (long long)GN * 512, nullptr, nullptr, 512, GN);

    // 9. dTb = bf16(hsT @ wt^T + bt) + fused BN stat partials  [NEW engine]
    mm256_k<2, 1, false, true><<<dim3(128, 2, 1), 512, 0, stream>>>(
        hsT, 512, 0, wtb, 512, 0, bt, 0, nullptr, 0, nullptr,
        dTb, 0, bs1, bs2, 512, 512);

    // 10. BN scale/shift from fused stats
    bn2_k<<<512, 256, 0, stream>>>(bs1, bs2, gamma, beta, bnsc, bnsh);

    // 11. h4T = bf16(h3b + relu(bn(dTb)))
    bn_apply_k<<<16384, 256, 0, stream>>>(h3b, dTb, bnsc, bnsh, h4T);

    // 12. fused final conv + per-wave-tile col max -> Pmax [16,1024,32]  [NEW engine]
    mm256_k<5, 1, false><<<dim3(128, 4, 1), 512, 0, stream>>>(
        h4T, 512, 0, w4b, 512, 0, b4, 0, nullptr, 0, nullptr,
        nullptr, 0, Pmax, nullptr, 1024, 512);

    // 13. out = max over tiles
    max_final_k<<<64, 256, 0, stream>>>(Pmax, out);
}

// Round 3
// 461.474 us; speedup vs baseline: 1.0326x; 1.0326x over previous
//
#include <hip/hip_runtime.h>
#include <cmath>

#define GN 2048
#define GB 16

typedef __attribute__((ext_vector_type(8))) short bf8_t;
typedef __attribute__((ext_vector_type(4))) float f4_t;

__device__ __forceinline__ short f2bf(float f) {
    union { float f; unsigned u; } v; v.f = f;
    unsigned r = v.u + 0x7FFFu + ((v.u >> 16) & 1u);
    return (short)(r >> 16);
}
__device__ __forceinline__ float bf2f(short s) {
    union { unsigned u; float f; } v; v.u = ((unsigned)(unsigned short)s) << 16;
    return v.f;
}

// async 16B/lane global->LDS (wave-uniform LDS base, lane i lands at base+i*16)
__device__ __forceinline__ void load16_lds(const short* g, short* l) {
    __builtin_amdgcn_global_load_lds(
        (const __attribute__((address_space(1))) unsigned int*)g,
        (__attribute__((address_space(3))) unsigned int*)l, 16, 0, 0);
}

// ---------------- reductions ----------------
__device__ __forceinline__ float wave_max(float v) {
#pragma unroll
    for (int o = 32; o > 0; o >>= 1) v = fmaxf(v, __shfl_xor(v, o, 64));
    return v;
}
__device__ __forceinline__ float wave_sum(float v) {
#pragma unroll
    for (int o = 32; o > 0; o >>= 1) v += __shfl_xor(v, o, 64);
    return v;
}
__device__ __forceinline__ float block_sum(float v) {
    __shared__ float sm[4];
    v = wave_sum(v);
    if ((threadIdx.x & 63) == 0) sm[threadIdx.x >> 6] = v;
    __syncthreads();
    v = sm[0] + sm[1] + sm[2] + sm[3];
    __syncthreads();
    return v;
}

// ---------------- fused fp32 -> bf16 weight convert (dst region contiguous) ----------------
__global__ __launch_bounds__(256) void f2ball_k(
    const float* __restrict__ w2, const float* __restrict__ w3,
    const float* __restrict__ wqk, const float* __restrict__ wv,
    const float* __restrict__ wt, const float* __restrict__ w4,
    short* __restrict__ dst) {
    int i = blockIdx.x * 256 + threadIdx.x;
    if (i >= 1409024) return;
    float v;
    if (i < 32768) v = w2[i];
    else if (i < 294912) v = w3[i - 32768];
    else if (i < 360448) v = wqk[i - 294912];
    else if (i < 622592) v = wv[i - 360448];
    else if (i < 884736) v = wt[i - 622592];
    else v = w4[i - 884736];
    dst[i] = f2bf(v);
}

// ---------------- posenc + conv1 + relu -> h1T [32768, 128] bf16 ----------------
__global__ __launch_bounds__(256) void posenc_conv1_k(
    const float* __restrict__ x, const float* __restrict__ w1,
    const float* __restrict__ b1, short* __restrict__ h1) {
    __shared__ float w[128 * 21];
    __shared__ float bb[128];
    __shared__ float se[256][21];
    const int tid = threadIdx.x;
    for (int i = tid; i < 128 * 21; i += 256) w[i] = w1[i];
    if (tid < 128) bb[tid] = b1[tid];
    int p0 = blockIdx.x * 256;
    int p = p0 + tid, b = p >> 11, n = p & (GN - 1);
    const float* xb = x + (long)b * 3 * GN + n;
    float t0 = xb[0], t1 = xb[GN], t2 = xb[2 * GN];
    se[tid][0] = t0; se[tid][1] = t1; se[tid][2] = t2;
    se[tid][3] = sinf(t0); se[tid][4] = sinf(t1); se[tid][5] = sinf(t2);
    se[tid][6] = cosf(t0); se[tid][7] = cosf(t1); se[tid][8] = cosf(t2);
    se[tid][9] = sinf(2.f * t0); se[tid][10] = sinf(2.f * t1); se[tid][11] = sinf(2.f * t2);
    se[tid][12] = cosf(2.f * t0); se[tid][13] = cosf(2.f * t1); se[tid][14] = cosf(2.f * t2);
    se[tid][15] = sinf(4.f * t0); se[tid][16] = sinf(4.f * t1); se[tid][17] = sinf(4.f * t2);
    se[tid][18] = cosf(4.f * t0); se[tid][19] = cosf(4.f * t1); se[tid][20] = cosf(4.f * t2);
    __syncthreads();
    short* outb = h1 + (long)p0 * 128;
    for (int it = 0; it < 128; ++it) {
        int L = it * 256 + tid;
        int pl = L >> 7, o = L & 127;
        float s = bb[o];
        const float* er = se[pl];
        const float* wr = &w[o * 21];
#pragma unroll
        for (int c = 0; c < 21; ++c) s = fmaf(wr[c], er[c], s);
        outb[L] = f2bf(fmaxf(s, 0.f));
    }
}

// ---------------- MFMA GEMM: D[row,col] = sum_k A[row,k]*B[col,k] ----------------
// R14 engine: 256 threads, 128x128 block tile, BK=64, single-buffered LDS via
// global_load_lds, 2-barrier loop with explicit vmcnt(0) drain. Kept for the
// small/odd-shaped GEMMs (steps 2, 5, 6, 7, 8a) where 32KB LDS -> 3+ blocks/CU
// occupancy beats the deep pipeline.
template <int MODE, int BIAS, bool RELU, bool STATS = false, bool COLMAX = false>
__global__ __launch_bounds__(256) void mm_k(
    const short* __restrict__ A, int lda, long long aB,
    const short* __restrict__ B, int ldb, long long bB,
    const float* __restrict__ bias, int biasStride,
    const short* __restrict__ aux, long long auxB,
    const float* __restrict__ rsv,
    float* __restrict__ Cf, long long cfB,
    short* __restrict__ Cb, long long cbB,
    float* __restrict__ Pmax, float* __restrict__ Ps2,
    int ldc, int K) {
    const int z = blockIdx.z;
    A += (long long)z * aB;
    B += (long long)z * bB;
    if (MODE == 4) { aux += (long long)z * auxB; rsv += (long long)z * GN; }
    if (MODE == 1) Cf += (long long)z * cfB;
    if (MODE == 2 || MODE == 4 || MODE == 6) Cb += (long long)z * cbB;
    if (MODE == 6) Pmax += (long long)z * GN * 32;
    const int row0 = blockIdx.x * 128, col0 = blockIdx.y * 128;
    const int tid = threadIdx.x;
    const int lane = tid & 63, w = tid >> 6;
    const int r = lane & 15, q = lane >> 4;
    const int wr = w >> 1, wc = w & 1;

    __shared__ short lA[8192];
    __shared__ short lB[8192];

    f4_t acc[4][4] = {};

    const int sRow = lane >> 2;
    const int sKb = (lane & 3) ^ ((lane >> 3) & 3);
    const long aG = (long)(row0 + w * 32 + sRow) * lda + sKb * 8;
    const long bG = (long)(col0 + w * 32 + sRow) * ldb + sKb * 8;
    short* ldsA0 = lA + (w * 32) * 32;
    short* ldsA1 = lA + (w * 32 + 16) * 32;
    short* ldsB0 = lB + (w * 32) * 32;
    short* ldsB1 = lB + (w * 32 + 16) * 32;

    const int sw = (q ^ ((r >> 1) & 3)) * 8;
    int aoff[4], boff[4];
#pragma unroll
    for (int i = 0; i < 4; ++i) {
        aoff[i] = (wr * 64 + i * 16 + r) * 32 + sw;
        boff[i] = (wc * 64 + i * 16 + r) * 32 + sw;
    }

    for (int k0 = 0; k0 < K; k0 += 64) {
        __syncthreads();
        load16_lds(A + aG + k0, ldsA0);
        load16_lds(A + aG + (long)16 * lda + k0, ldsA1);
        load16_lds(B + bG + k0, ldsB0);
        load16_lds(B + bG + (long)16 * ldb + k0, ldsB1);
        load16_lds(A + aG + k0 + 32, ldsA0 + 4096);
        load16_lds(A + aG + (long)16 * lda + k0 + 32, ldsA1 + 4096);
        load16_lds(B + bG + k0 + 32, ldsB0 + 4096);
        load16_lds(B + bG + (long)16 * ldb + k0 + 32, ldsB1 + 4096);
        asm volatile("s_waitcnt vmcnt(0)" ::: "memory");
        __syncthreads();
#pragma unroll
        for (int h = 0; h < 2; ++h) {
            const short* la = lA + h * 4096;
            const short* lb = lB + h * 4096;
            bf8_t av[4], bv[4];
#pragma unroll
            for (int i = 0; i < 4; ++i) av[i] = *(const bf8_t*)(la + aoff[i]);
#pragma unroll
            for (int j = 0; j < 4; ++j) bv[j] = *(const bf8_t*)(lb + boff[j]);
#pragma unroll
            for (int i = 0; i < 4; ++i)
#pragma unroll
                for (int j = 0; j < 4; ++j)
                    acc[i][j] = __builtin_amdgcn_mfma_f32_16x16x32_bf16(av[i], bv[j], acc[i][j], 0, 0, 0);
        }
    }

    if constexpr (MODE == 5) {
        int b = row0 >> 11;
        int rw = (blockIdx.x * 2 + wr) & 31;
#pragma unroll
        for (int j = 0; j < 4; ++j) {
            float vm = -1e30f;
#pragma unroll
            for (int i = 0; i < 4; ++i)
#pragma unroll
                for (int e = 0; e < 4; ++e) vm = fmaxf(vm, acc[i][j][e]);
            vm = fmaxf(vm, __shfl_xor(vm, 16, 64));
            vm = fmaxf(vm, __shfl_xor(vm, 32, 64));
            if (q == 0) {
                int gcol = col0 + wc * 64 + j * 16 + r;
                Pmax[(((long)b * 1024 + gcol) << 5) + rw] = vm + bias[gcol];
            }
        }
    } else if constexpr (MODE == 6) {
        float rsum[4][4] = {};
#pragma unroll
        for (int j = 0; j < 4; ++j) {
            int gcol = col0 + wc * 64 + j * 16 + r;
#pragma unroll
            for (int i = 0; i < 4; ++i) {
#pragma unroll
                for (int e = 0; e < 4; ++e) {
                    int grow = row0 + wr * 64 + i * 16 + q * 4 + e;
                    float ex = __expf(acc[i][j][e]);
                    rsum[i][e] += ex;
                    Cb[(long)grow * ldc + gcol] = f2bf(ex);
                }
            }
        }
#pragma unroll
        for (int i = 0; i < 4; ++i)
#pragma unroll
            for (int e = 0; e < 4; ++e) {
                float v = rsum[i][e];
                v += __shfl_xor(v, 1, 64);
                v += __shfl_xor(v, 2, 64);
                v += __shfl_xor(v, 4, 64);
                v += __shfl_xor(v, 8, 64);
                if (r == 0) {
                    int grow = row0 + wr * 64 + i * 16 + q * 4 + e;
                    Pmax[((long)grow << 5) + blockIdx.y * 2 + wc] = v;
                }
            }
    } else if constexpr (MODE == 4) {
#pragma unroll
        for (int i = 0; i < 4; ++i) {
#pragma unroll
            for (int e = 0; e < 4; ++e) {
                int grow = row0 + wr * 64 + i * 16 + q * 4 + e;
                float rsr = rsv[grow];
                long ob = (long)grow * ldc + col0 + wc * 64 + r;
#pragma unroll
                for (int j = 0; j < 4; ++j) {
                    long off = ob + j * 16;
                    Cb[off] = f2bf(bf2f(aux[off]) - acc[i][j][e] * rsr);
                }
            }
        }
    } else {
        const int b2d = (BIAS == 3) ? (row0 >> 11) : 0;
#pragma unroll
        for (int j = 0; j < 4; ++j) {
            int gcol = col0 + wc * 64 + j * 16 + r;
            float bvv = 0.f;
            if constexpr (BIAS == 1) bvv = bias[gcol];
            if constexpr (BIAS == 3) bvv = bias[b2d * biasStride + gcol];
            float s1 = 0.f, s2 = 0.f;
            float cmx = -1e30f;
#pragma unroll
            for (int i = 0; i < 4; ++i) {
#pragma unroll
                for (int e = 0; e < 4; ++e) {
                    int grow = row0 + wr * 64 + i * 16 + q * 4 + e;
                    float v = acc[i][j][e] + bvv;
                    if constexpr (BIAS == 2) v += bias[grow];
                    if constexpr (RELU) v = fmaxf(v, 0.f);
                    if constexpr (STATS) { s1 += v; s2 = fmaf(v, v, s2); }
                    if constexpr (COLMAX) cmx = fmaxf(cmx, v);
                    long off = (long)grow * ldc + gcol;
                    if constexpr (MODE == 1) Cf[off] = v;
                    if constexpr (MODE == 2) Cb[off] = f2bf(v);
                }
            }
            if constexpr (STATS) {
                s1 += __shfl_xor(s1, 16, 64); s1 += __shfl_xor(s1, 32, 64);
                s2 += __shfl_xor(s2, 16, 64); s2 += __shfl_xor(s2, 32, 64);
                if (q == 0) {
                    int rw2 = blockIdx.x * 2 + wr;
                    Pmax[rw2 * 512 + gcol] = s1;
                    Ps2[rw2 * 512 + gcol] = s2;
                }
            }
            if constexpr (COLMAX) {
                cmx = fmaxf(cmx, __shfl_xor(cmx, 16, 64));
                cmx = fmaxf(cmx, __shfl_xor(cmx, 32, 64));
                if (q == 0) {
                    int b = row0 >> 11;
                    int rw = (blockIdx.x * 2 + wr) & 31;
                    Pmax[(((long)b * ldc + gcol) << 5) + rw] = cmx;
                }
            }
        }
    }
}

// ================= 256x256 deep-pipelined MFMA GEMM engine (T2+T3+T4+T5) ======
// R3: TWO phases per K-tile (was 4) -> 4 barriers + 1 vmcnt per tile (was 8+2).
// Phase A: ds_read Ah0,Bh0,Bh1 (16xb128), MFMA quadrants (0,0)+(0,1) (32 MFMA);
//          stages Ah1/Bh1(t+1) [WAR: last read t-1 phB / t-1 phA, >=1 barrier].
// Phase B: ds_read Ah1 (8xb128), MFMA quadrants (1,0)+(1,1) (32 MFMA, bv0/bv1
//          held from phA); stages Ah0/Bh0(t+2) into CURRENT buf [WAR: last read
//          this tile's phA, 1 barrier]; single counted vmcnt(4) -> tile t+1 fully
//          landed, A0B0(t+2) (4 loads) stays in flight across the barrier.
// LDS layout/swizzle unchanged from R1 (verified, 0 bank conflicts).
__device__ __forceinline__ void stage2(const short* g0, const short* g1, short* dst) {
    load16_lds(g0, dst);
    load16_lds(g1, dst + 4096);
}

template <int MH, int NH>
__device__ __forceinline__ void mfma_quad(const bf8_t (&av)[4][2], const bf8_t (&bv)[2][2],
                                          f4_t (&acc)[8][4]) {
#pragma unroll
    for (int mi = 0; mi < 4; ++mi)
#pragma unroll
        for (int ni = 0; ni < 2; ++ni) {
            acc[MH * 4 + mi][NH * 2 + ni] = __builtin_amdgcn_mfma_f32_16x16x32_bf16(
                av[mi][0], bv[ni][0], acc[MH * 4 + mi][NH * 2 + ni], 0, 0, 0);
            acc[MH * 4 + mi][NH * 2 + ni] = __builtin_amdgcn_mfma_f32_16x16x32_bf16(
                av[mi][1], bv[ni][1], acc[MH * 4 + mi][NH * 2 + ni], 0, 0, 0);
        }
}

__device__ __forceinline__ void rd4(const short* p, int swz0, int swz1, bf8_t (&v)[4][2]) {
#pragma unroll
    for (int i = 0; i < 4; ++i) {
        v[i][0] = *(const bf8_t*)(p + i * 1024 + swz0);
        v[i][1] = *(const bf8_t*)(p + i * 1024 + swz1);
    }
}
__device__ __forceinline__ void rd2(const short* p, int swz0, int swz1, bf8_t (&v)[2][2]) {
#pragma unroll
    for (int i = 0; i < 2; ++i) {
        v[i][0] = *(const bf8_t*)(p + i * 1024 + swz0);
        v[i][1] = *(const bf8_t*)(p + i * 1024 + swz1);
    }
}

#define SB0 __builtin_amdgcn_sched_barrier(0)
#define BARRIER asm volatile("s_barrier" ::: "memory")

// MODE: 2=Cb=bf16(D+bias) [opt STATS], 4=Cb=bf16(aux - rs[row]*D), 5=col-max partials
template <int MODE, int BIAS, bool RELU, bool STATS = false>
__global__ __launch_bounds__(512, 2) void mm256_k(
    const short* __restrict__ A, int lda, long long aB,
    const short* __restrict__ B, int ldb, long long bB,
    const float* __restrict__ bias, int biasStride,
    const short* __restrict__ aux, long long auxB,
    const float* __restrict__ rsv,
    short* __restrict__ Cb, long long cbB,
    float* __restrict__ Pmax, float* __restrict__ Ps2,
    int ldc, int K) {
    __shared__ short lA[32768];
    __shared__ short lB[32768];
    const int bx = blockIdx.x, by = blockIdx.y, bz = blockIdx.z;
    const int z = bz;
    A += (long long)z * aB;
    B += (long long)z * bB;
    if constexpr (MODE == 4) { aux += (long long)z * auxB; rsv += (long long)z * GN; }
    if constexpr (MODE != 5) Cb += (long long)z * cbB;
    const int row0 = bx * 256, col0 = by * 256;
    const int tid = threadIdx.x;
    const int lane = tid & 63, w = tid >> 6;
    const int r16 = lane & 15, q = lane >> 4;
    const int wr = w >> 2, wc = w & 3;

    // ---- staging sources (pre-swizzled k-slot so linear LDS dest => swizzled layout)
    const int rc0 = w * 8 + (lane >> 3);            // row-in-half, call0 (call1 = +64)
    const int s8 = ((lane & 7) ^ (rc0 & 7)) * 8;    // swizzled 16B k-slot (shorts)
    const long ldA64 = (long)64 * lda, ldB64 = (long)64 * ldb;
    const short* aH0 = A + (long)(row0 + rc0) * lda + s8;
    const short* aH1 = aH0 + (long)128 * lda;
    const short* bH0 = B + (long)(col0 + rc0) * ldb + s8;
    const short* bH1 = bH0 + (long)128 * ldb;
    short* dA = lA + w * 512;   // wave-uniform LDS chunk base (1 KB/wave/call)
    short* dB = lB + w * 512;

#define STG_A(d_, h_, kt_) stage2((h_ ? aH1 : aH0) + (long)(kt_) * 64,                      \
                                  (h_ ? aH1 : aH0) + (long)(kt_) * 64 + ldA64,              \
                                  dA + (d_) * 16384 + (h_) * 8192)
#define STG_B(d_, h_, kt_) stage2((h_ ? bH1 : bH0) + (long)(kt_) * 64,                      \
                                  (h_ ? bH1 : bH0) + (long)(kt_) * 64 + ldB64,              \
                                  dB + (d_) * 16384 + (h_) * 8192)

    // ---- fragment read offsets (swizzle XOR depends only on r16&7)
    const int swz0 = (q ^ (r16 & 7)) * 8;         // ks=0
    const int swz1 = ((4 + q) ^ (r16 & 7)) * 8;   // ks=1
    const int arow = (wr * 64 + r16) * 64;
    const int brow = (wc * 32 + r16) * 64;

    f4_t acc[8][4] = {};
    bf8_t av[4][2], bv0[2][2], bv1[2][2];
    const int NT = K >> 6;

    // ---- prologue: tile0 all 4 halves + tile1 A0B0 (if any)
    STG_A(0, 0, 0); STG_B(0, 0, 0); STG_A(0, 1, 0); STG_B(0, 1, 0);
    if (NT > 1) {
        STG_A(1, 0, 1); STG_B(1, 0, 1);
        asm volatile("s_waitcnt vmcnt(4)" ::: "memory");  // tile0 landed, tile1 A0B0 in flight
    } else {
        asm volatile("s_waitcnt vmcnt(0)" ::: "memory");
    }
    SB0; BARRIER; SB0;

    for (int t = 0; t < NT; ++t) {
        const int d = t & 1;
        const short* la = lA + d * 16384;
        const short* lb = lB + d * 16384;
        // ---- phase A: quadrants (0,0),(0,1); reads Ah0,Bh0,Bh1; stages A1B1(t+1)
        rd4(la + arow, swz0, swz1, av);
        rd2(lb + brow, swz0, swz1, bv0);
        rd2(lb + 8192 + brow, swz0, swz1, bv1);
        if (t + 1 < NT) { STG_A(d ^ 1, 1, t + 1); STG_B(d ^ 1, 1, t + 1); }
        SB0; BARRIER; SB0;
        __builtin_amdgcn_s_setprio(1);
        mfma_quad<0, 0>(av, bv0, acc);
        mfma_quad<0, 1>(av, bv1, acc);
        __builtin_amdgcn_s_setprio(0);
        SB0; BARRIER; SB0;
        // ---- phase B: quadrants (1,0),(1,1); reads Ah1; stages A0B0(t+2); 1 counted wait
        rd4(la + 8192 + arow, swz0, swz1, av);
        if (t + 2 < NT) {
            STG_A(d, 0, t + 2); STG_B(d, 0, t + 2);
            asm volatile("s_waitcnt vmcnt(4)" ::: "memory");  // tile t+1 fully landed
        } else if (t + 1 < NT) {
            asm volatile("s_waitcnt vmcnt(0)" ::: "memory");  // drain for final tile
        }
        SB0; BARRIER; SB0;
        __builtin_amdgcn_s_setprio(1);
        mfma_quad<1, 0>(av, bv0, acc);
        mfma_quad<1, 1>(av, bv1, acc);
        __builtin_amdgcn_s_setprio(0);
        SB0; BARRIER; SB0;
    }
#undef STG_A
#undef STG_B

    // ---- epilogues ----
    const int mrow = row0 + wr * 64 + q * 4;   // + mh*128 + mi*16 + e
    const int ncol = col0 + wc * 32 + r16;     // + nh*128 + ni*16

    if constexpr (MODE == 4) {
#pragma unroll
        for (int m = 0; m < 8; ++m) {
#pragma unroll
            for (int e = 0; e < 4; ++e) {
                const int grow = mrow + (m >> 2) * 128 + (m & 3) * 16 + e;
                const float rsr = rsv[grow];
                const long rb = (long)grow * ldc;
#pragma unroll
                for (int n = 0; n < 4; ++n) {
                    const long off = rb + ncol + (n >> 1) * 128 + (n & 1) * 16;
                    Cb[off] = f2bf(bf2f(aux[off]) - acc[m][n][e] * rsr);
                }
            }
        }
    } else if constexpr (MODE == 2) {
        const int b2d = (BIAS == 3) ? (row0 >> 11) : 0;
#pragma unroll
        for (int n = 0; n < 4; ++n) {
            const int gcol = ncol + (n >> 1) * 128 + (n & 1) * 16;
            float bvv = 0.f;
            if constexpr (BIAS == 1) bvv = bias[gcol];
            if constexpr (BIAS == 3) bvv = bias[b2d * biasStride + gcol];
#pragma unroll
            for (int mh = 0; mh < 2; ++mh) {
                float s1 = 0.f, s2 = 0.f;
#pragma unroll
                for (int mi = 0; mi < 4; ++mi) {
#pragma unroll
                    for (int e = 0; e < 4; ++e) {
                        const int grow = mrow + mh * 128 + mi * 16 + e;
                        float v = acc[mh * 4 + mi][n][e] + bvv;
                        if constexpr (BIAS == 2) v += bias[grow];
                        if constexpr (RELU) v = fmaxf(v, 0.f);
                        if constexpr (STATS) { s1 += v; s2 = fmaf(v, v, s2); }
                        Cb[(long)grow * ldc + gcol] = f2bf(v);
                    }
                }
                if constexpr (STATS) {
                    s1 += __shfl_xor(s1, 16, 64); s1 += __shfl_xor(s1, 32, 64);
                    s2 += __shfl_xor(s2, 16, 64); s2 += __shfl_xor(s2, 32, 64);
                    if (q == 0) {
                        const int rw2 = bx * 4 + mh * 2 + wr;  // 64-row group
                        Pmax[rw2 * 512 + gcol] = s1;
                        Ps2[rw2 * 512 + gcol] = s2;
                    }
                }
            }
        }
    } else if constexpr (MODE == 5) {
        const int b = row0 >> 11;
#pragma unroll
        for (int n = 0; n < 4; ++n) {
            const int gcol = ncol + (n >> 1) * 128 + (n & 1) * 16;
            const float bvv = bias[gcol];
#pragma unroll
            for (int mh = 0; mh < 2; ++mh) {
                float vm = -1e30f;
#pragma unroll
                for (int mi = 0; mi < 4; ++mi)
#pragma unroll
                    for (int e = 0; e < 4; ++e) vm = fmaxf(vm, acc[mh * 4 + mi][n][e]);
                vm = fmaxf(vm, __shfl_xor(vm, 16, 64));
                vm = fmaxf(vm, __shfl_xor(vm, 32, 64));
                if (q == 0) {
                    const int rw = (bx * 4 + mh * 2 + wr) & 31;
                    Pmax[(((long)b * ldc + gcol) << 5) + rw] = vm + bvv;
                }
            }
        }
    }
}
#undef SB0
#undef BARRIER

// ---------------- rs[q] = 1 / sum of 32 row partials ----------------
__global__ __launch_bounds__(256) void rs_k(const float* __restrict__ rp,
                                            float* __restrict__ rs) {
    int i = blockIdx.x * 256 + threadIdx.x;
    const float* p = rp + ((long)i << 5);
    float s = 0.f;
#pragma unroll
    for (int j = 0; j < 32; ++j) s += p[j];
    rs[i] = 1.f / s;
}

// ---------------- g[i] = max over 32 partials ----------------
__global__ __launch_bounds__(256) void maxg_k(const float* __restrict__ P,
                                              float* __restrict__ g) {
    int i = blockIdx.x * 256 + threadIdx.x;
    const float* p = P + ((long)i << 5);
    float m = p[0];
#pragma unroll
    for (int j = 1; j < 32; ++j) m = fmaxf(m, p[j]);
    g[i] = m;
}

// ---------------- cvec[b,o] = b3[o] + sum_c w3[o,256+c]*g[b,c] (fp32) ----------------
__global__ __launch_bounds__(256) void cvec_k(const float* __restrict__ w3,
                                              const float* __restrict__ b3,
                                              const float* __restrict__ g,
                                              float* __restrict__ cvec) {
    int idx = blockIdx.x * 256 + threadIdx.x;
    int b = idx >> 9, o = idx & 511;
    const float* gb = g + (b << 8);
    const float* wr = w3 + (long)o * 512 + 256;
    float s = b3[o];
    for (int c = 0; c < 256; ++c) s = fmaf(wr[c], gb[c], s);
    cvec[idx] = s;
}

// ---------------- column sums of attn = P * rs[q] over q (two-stage) ----------------
// vectorized: 16B/lane coalesced reads, 8 columns per thread
__global__ __launch_bounds__(256) void colsum1_k(const short* __restrict__ Ab,
                                                 const float* __restrict__ rs,
                                                 float* __restrict__ cp) {
    const int qs = blockIdx.x, z = blockIdx.y;
    const int k0 = threadIdx.x * 8;
    const short* p = Ab + (long)z * GN * GN + (long)qs * 64 * GN + k0;
    const float* rv = rs + z * GN + qs * 64;
    float s[8] = {};
    for (int qq = 0; qq < 64; ++qq) {
        uint4 v = *(const uint4*)(p + (long)qq * GN);
        const float rr = rv[qq];
        const short* sp = (const short*)&v;
#pragma unroll
        for (int j = 0; j < 8; ++j) s[j] = fmaf(bf2f(sp[j]), rr, s[j]);
    }
    float* o = cp + ((long)(z * 32 + qs) * GN) + k0;
#pragma unroll
    for (int j = 0; j < 8; ++j) o[j] = s[j];
}
__global__ __launch_bounds__(256) void colsum2_k(const float* __restrict__ cp,
                                                 float* __restrict__ cs) {
    int k = blockIdx.x * 256 + threadIdx.x, z = blockIdx.y;
    float s = 1e-9f;
    for (int qs = 0; qs < 32; ++qs) s += cp[((z * 32 + qs) * GN) + k];
    cs[z * GN + k] = s;
}

// ---------------- xvc[c,p] /= cs[p]  (in place) ----------------
__global__ __launch_bounds__(256) void xvscale_k(short* __restrict__ xvc,
                                                 const float* __restrict__ cs) {
    long idx = ((long)blockIdx.x * 256 + threadIdx.x) * 4;
    int p = (int)(idx & 32767);
    short* ptr = xvc + idx;
    float4 cv = *(const float4*)(cs + p);
    uint2 u = *(const uint2*)ptr;
    short* sp = (short*)&u;
    sp[0] = f2bf(bf2f(sp[0]) / cv.x);
    sp[1] = f2bf(bf2f(sp[1]) / cv.y);
    sp[2] = f2bf(bf2f(sp[2]) / cv.z);
    sp[3] = f2bf(bf2f(sp[3]) / cv.w);
    *(uint2*)ptr = u;
}

// ---------------- BN scale/shift from fused GEMM stats [512][512] ----------------
__global__ __launch_bounds__(256) void bn2_k(const float* __restrict__ bs1,
                                             const float* __restrict__ bs2,
                                             const float* __restrict__ gamma,
                                             const float* __restrict__ beta,
                                             float* __restrict__ sc,
                                             float* __restrict__ sh) {
    int c = blockIdx.x;
    float s = 0.f, s2 = 0.f;
    for (int i = threadIdx.x; i < 512; i += 256) {
        s += bs1[i * 512 + c];
        s2 += bs2[i * 512 + c];
    }
    s = block_sum(s);
    s2 = block_sum(s2);
    if (threadIdx.x == 0) {
        const float cnt = (float)(GB * GN);
        float mu = s / cnt;
        float var = s2 / cnt - mu * mu;
        float r = rsqrtf(var + 1e-5f);
        float gm = gamma[c] * r;
        sc[c] = gm;
        sh[c] = beta[c] - gm * mu;
    }
}

// ---------------- h4T = bf16(h3b + relu(d*sc+sh)) ----------------
__global__ __launch_bounds__(256) void bn_apply_k(const short* __restrict__ h3b,
                                                  const short* __restrict__ d,
                                                  const float* __restrict__ sc,
                                                  const float* __restrict__ sh,
                                                  short* __restrict__ h4) {
    long bidx = ((long)blockIdx.x * 256 + threadIdx.x) * 4;
    int c = (int)(bidx & 511);
    uint2 du = *(const uint2*)(d + bidx);
    short* ds = (short*)&du;
    uint2 hu = *(const uint2*)(h3b + bidx);
    short* hs = (short*)&hu;
    float4 a4 = *(const float4*)(sc + c);
    float4 b4 = *(const float4*)(sh + c);
    float r0 = bf2f(hs[0]) + fmaxf(fmaf(bf2f(ds[0]), a4.x, b4.x), 0.f);
    float r1 = bf2f(hs[1]) + fmaxf(fmaf(bf2f(ds[1]), a4.y, b4.y), 0.f);
    float r2 = bf2f(hs[2]) + fmaxf(fmaf(bf2f(ds[2]), a4.z, b4.z), 0.f);
    float r3 = bf2f(hs[3]) + fmaxf(fmaf(bf2f(ds[3]), a4.w, b4.w), 0.f);
    uint2 o;
    o.x = (unsigned short)f2bf(r0) | ((unsigned)(unsigned short)f2bf(r1) << 16);
    o.y = (unsigned short)f2bf(r2) | ((unsigned)(unsigned short)f2bf(r3) << 16);
    *(uint2*)(h4 + bidx) = o;
}

// ---------------- out[i] = max over 32 partials ----------------
__global__ __launch_bounds__(256) void max_final_k(const float* __restrict__ P,
                                                   float* __restrict__ out) {
    int i = blockIdx.x * 256 + threadIdx.x;
    const float* p = P + ((long)i << 5);
    float m = p[0];
#pragma unroll
    for (int j = 1; j < 32; ++j) m = fmaxf(m, p[j]);
    out[i] = m;
}

extern "C" void kernel_launch(void* const* d_in, const int* in_sizes, int n_in,
                              void* d_out, int out_size, void* d_ws, size_t ws_size,
                              hipStream_t stream) {
    const float* x = (const float*)d_in[0];
    const float* w1 = (const float*)d_in[1];
    const float* b1 = (const float*)d_in[2];
    const float* w2 = (const float*)d_in[3];
    const float* b2 = (const float*)d_in[4];
    const float* w3 = (const float*)d_in[5];
    const float* b3 = (const float*)d_in[6];
    const float* w4 = (const float*)d_in[7];
    const float* b4 = (const float*)d_in[8];
    const float* wqk = (const float*)d_in[9];
    const float* wv = (const float*)d_in[10];
    const float* bv = (const float*)d_in[11];
    const float* wt = (const float*)d_in[12];
    const float* bt = (const float*)d_in[13];
    const float* gamma = (const float*)d_in[14];
    const float* beta = (const float*)d_in[15];
    float* out = (float*)d_out;

    // ---- workspace carve (bytes), peak ~255.05 MB (unchanged) ----
    char* base = (char*)d_ws;
    short* h3b = (short*)base;                    // [32768,512] bf16 32 MB
    short* hsT = (short*)(base + 33554432);       // [32768,512] bf16 32 MB
    short* kT  = (short*)(base + 67108864);       // [32768,128] bf16  8 MB
    short* xvc = (short*)(base + 75497472);       // [512,32768] bf16 32 MB (channel-major)
    short* EA  = (short*)(base + 109051904);      // [16,2048,2048] bf16 128 MB (P = exp(E))
    short* h1T = (short*)(base + 109051904);      //   alias (early, dead before EA)
    short* h2T = (short*)(base + 117440512);      //   alias (early)
    short* dTb = (short*)(base + 109051904);      //   alias [32768,512] bf16 (late, EA dead)
    short* h4T = (short*)(base + 67108864);       //   alias 32 MB over kT+xvc (late)
    char* S = base + 243269632;
    float* g    = (float*)(S + 262144);           // 16384
    float* cvec = (float*)(S + 278528);           // 32768
    float* cp   = (float*)(S + 311296);           // 4 MB [16,32,2048]; rp aliases (earlier)
    float* rp   = cp;                             //   [32768,32] row-sum partials
    float* cs   = (float*)(S + 4505600);          // 128 KB [16,2048]
    float* bs1  = (float*)(S + 4636672);          // 1 MB [512,512] fused BN sum partials
    float* bs2  = (float*)(S + 5685248);          // 1 MB [512,512] fused BN sumsq partials
    float* bnsc = (float*)(S + 6733824);          // 2048
    float* bnsh = (float*)(S + 6735872);          // 2048
    float* Pmax = (float*)(S + 6737920);          // 2 MB partials
    short* w2b  = (short*)(S + 8835072);          // bf16 weights, CONTIGUOUS region
    short* w3b  = (short*)(S + 8900608);
    short* wqkb = (short*)(S + 9424896);
    short* wvb  = (short*)(S + 9555968);
    short* wtb  = (short*)(S + 10080256);
    short* w4b  = (short*)(S + 10604544);
    float* rs   = (float*)(S + 11653120);         // 128 KB [16,2048] 1/rowsum

    // 0. all weight converts in one kernel
    f2ball_k<<<5505, 256, 0, stream>>>(w2, w3, wqk, wv, wt, w4, w2b);

    // 1. posenc + conv1 + relu -> h1T
    posenc_conv1_k<<<128, 256, 0, stream>>>(x, w1, b1, h1T);

    // 2. h2T = h1T @ w2^T + b2 + fused per-batch col-max partials (old engine)
    mm_k<2, 1, false, false, true><<<dim3(256, 2, 1), 256, 0, stream>>>(
        h1T, 128, 0, w2b, 128, 0, b2, 0, nullptr, 0, nullptr,
        nullptr, 0, h2T, 0, Pmax, nullptr, 256, 128);

    // 3. g[b,c] = max over 32 partials
    maxg_k<<<16, 256, 0, stream>>>(Pmax, g);

    // 4. cvec = w3[:,256:] @ g + b3 (fp32)
    cvec_k<<<32, 256, 0, stream>>>(w3, b3, g, cvec);

    // 5. h3b = bf16(relu(h2T @ w3[:,:256]^T + cvec))  [old engine — 3 blocks/CU wins at K=256]
    mm_k<2, 3, true><<<dim3(256, 4, 1), 256, 0, stream>>>(
        h2T, 256, 0, w3b, 512, 0, cvec, 512, nullptr, 0, nullptr,
        nullptr, 0, h3b, 0, nullptr, nullptr, 512, 256);

    // 6. kT = h3b @ wqk^T (cols=128 < 256: old engine)
    mm_k<2, 0, false><<<dim3(256, 1, 1), 256, 0, stream>>>(
        h3b, 512, 0, wqkb, 512, 0, nullptr, 0, nullptr, 0, nullptr,
        nullptr, 0, kT, 0, nullptr, nullptr, 128, 512);

    // 7. xv channel-major: D[c, point] = wv @ h3 + bv(row)  [old engine]
    mm_k<2, 2, false><<<dim3(4, 256, 1), 256, 0, stream>>>(
        wvb, 512, 0, h3b, 512, 0, bv, 0, nullptr, 0, nullptr,
        nullptr, 0, xvc, 0, nullptr, nullptr, 32768, 512);

    // 8a. P = exp(kT kT^T) bf16 + row-sum partials rp (old engine)
    mm_k<6, 0, false><<<dim3(16, 16, 16), 256, 0, stream>>>(
        kT, 128, (long long)GN * 128, kT, 128, (long long)GN * 128,
        nullptr, 0, nullptr, 0, nullptr, nullptr, 0,
        EA, (long long)GN * GN, rp, nullptr, GN, 128);
    // 8b. rs = 1/rowsum
    rs_k<<<128, 256, 0, stream>>>(rp, rs);
    // 8c. column sums of attn = P*rs (vectorized)
    colsum1_k<<<dim3(32, GB), 256, 0, stream>>>(EA, rs, cp);
    colsum2_k<<<dim3(8, GB), 256, 0, stream>>>(cp, cs);
    // 8d. fold L1 renorm into xv (in place)
    xvscale_k<<<16384, 256, 0, stream>>>(xvc, cs);
    // 8e. hsT = bf16(h3b - rs[q] * (P @ xv'^T))  [2-phase engine, NO swizzle]
    mm256_k<4, 0, false><<<dim3(8, 2, 16), 512, 0, stream>>>(
        EA, GN, (long long)GN * GN,
        xvc, 32768, (long long)GN,
        nullptr, 0, h3b, (long long)GN * 512, rs,
        hsT, (long long)GN * 512, nullptr, nullptr, 512, GN);

    // 9. dTb = bf16(hsT @ wt^T + bt) + fused BN stat partials  [2-phase engine]
    mm256_k<2, 1, false, true><<<dim3(128, 2, 1), 512, 0, stream>>>(
        hsT, 512, 0, wtb, 512, 0, bt, 0, nullptr, 0, nullptr,
        dTb, 0, bs1, bs2, 512, 512);

    // 10. BN scale/shift from fused stats
    bn2_k<<<512, 256, 0, stream>>>(bs1, bs2, gamma, beta, bnsc, bnsh);

    // 11. h4T = bf16(h3b + relu(bn(dTb)))
    bn_apply_k<<<16384, 256, 0, stream>>>(h3b, dTb, bnsc, bnsh, h4T);

    // 12. fused final conv + per-wave-tile col max -> Pmax [16,1024,32]  [2-phase engine]
    mm256_k<5, 1, false><<<dim3(128, 4, 1), 512, 0, stream>>>(
        h4T, 512, 0, w4b, 512, 0, b4, 0, nullptr, 0, nullptr,
        nullptr, 0, Pmax, nullptr, 1024, 512);

    // 13. out = max over tiles
    max_final_k<<<64, 256, 0, stream>>>(Pmax, out);
}

// Round 4
// 458.247 us; speedup vs baseline: 1.0399x; 1.0070x over previous
//
#include <hip/hip_runtime.h>
#include <cmath>

#define GN 2048
#define GB 16

typedef __attribute__((ext_vector_type(8))) short bf8_t;
typedef __attribute__((ext_vector_type(4))) float f4_t;

__device__ __forceinline__ short f2bf(float f) {
    union { float f; unsigned u; } v; v.f = f;
    unsigned r = v.u + 0x7FFFu + ((v.u >> 16) & 1u);
    return (short)(r >> 16);
}
__device__ __forceinline__ float bf2f(short s) {
    union { unsigned u; float f; } v; v.u = ((unsigned)(unsigned short)s) << 16;
    return v.f;
}

// async 16B/lane global->LDS (wave-uniform LDS base, lane i lands at base+i*16)
__device__ __forceinline__ void load16_lds(const short* g, short* l) {
    __builtin_amdgcn_global_load_lds(
        (const __attribute__((address_space(1))) unsigned int*)g,
        (__attribute__((address_space(3))) unsigned int*)l, 16, 0, 0);
}

// ---------------- reductions ----------------
__device__ __forceinline__ float wave_max(float v) {
#pragma unroll
    for (int o = 32; o > 0; o >>= 1) v = fmaxf(v, __shfl_xor(v, o, 64));
    return v;
}
__device__ __forceinline__ float wave_sum(float v) {
#pragma unroll
    for (int o = 32; o > 0; o >>= 1) v += __shfl_xor(v, o, 64);
    return v;
}
__device__ __forceinline__ float block_sum(float v) {
    __shared__ float sm[4];
    v = wave_sum(v);
    if ((threadIdx.x & 63) == 0) sm[threadIdx.x >> 6] = v;
    __syncthreads();
    v = sm[0] + sm[1] + sm[2] + sm[3];
    __syncthreads();
    return v;
}

// ---------------- fused fp32 -> bf16 weight convert (dst region contiguous) ----------------
__global__ __launch_bounds__(256) void f2ball_k(
    const float* __restrict__ w2, const float* __restrict__ w3,
    const float* __restrict__ wqk, const float* __restrict__ wv,
    const float* __restrict__ wt, const float* __restrict__ w4,
    short* __restrict__ dst) {
    int i = blockIdx.x * 256 + threadIdx.x;
    if (i >= 1409024) return;
    float v;
    if (i < 32768) v = w2[i];
    else if (i < 294912) v = w3[i - 32768];
    else if (i < 360448) v = wqk[i - 294912];
    else if (i < 622592) v = wv[i - 360448];
    else if (i < 884736) v = wt[i - 622592];
    else v = w4[i - 884736];
    dst[i] = f2bf(v);
}

// ---------------- posenc + conv1 + relu -> h1T [32768, 128] bf16 ----------------
__global__ __launch_bounds__(256) void posenc_conv1_k(
    const float* __restrict__ x, const float* __restrict__ w1,
    const float* __restrict__ b1, short* __restrict__ h1) {
    __shared__ float w[128 * 21];
    __shared__ float bb[128];
    __shared__ float se[256][21];
    const int tid = threadIdx.x;
    for (int i = tid; i < 128 * 21; i += 256) w[i] = w1[i];
    if (tid < 128) bb[tid] = b1[tid];
    int p0 = blockIdx.x * 256;
    int p = p0 + tid, b = p >> 11, n = p & (GN - 1);
    const float* xb = x + (long)b * 3 * GN + n;
    float t0 = xb[0], t1 = xb[GN], t2 = xb[2 * GN];
    se[tid][0] = t0; se[tid][1] = t1; se[tid][2] = t2;
    se[tid][3] = sinf(t0); se[tid][4] = sinf(t1); se[tid][5] = sinf(t2);
    se[tid][6] = cosf(t0); se[tid][7] = cosf(t1); se[tid][8] = cosf(t2);
    se[tid][9] = sinf(2.f * t0); se[tid][10] = sinf(2.f * t1); se[tid][11] = sinf(2.f * t2);
    se[tid][12] = cosf(2.f * t0); se[tid][13] = cosf(2.f * t1); se[tid][14] = cosf(2.f * t2);
    se[tid][15] = sinf(4.f * t0); se[tid][16] = sinf(4.f * t1); se[tid][17] = sinf(4.f * t2);
    se[tid][18] = cosf(4.f * t0); se[tid][19] = cosf(4.f * t1); se[tid][20] = cosf(4.f * t2);
    __syncthreads();
    short* outb = h1 + (long)p0 * 128;
    for (int it = 0; it < 128; ++it) {
        int L = it * 256 + tid;
        int pl = L >> 7, o = L & 127;
        float s = bb[o];
        const float* er = se[pl];
        const float* wr = &w[o * 21];
#pragma unroll
        for (int c = 0; c < 21; ++c) s = fmaf(wr[c], er[c], s);
        outb[L] = f2bf(fmaxf(s, 0.f));
    }
}

// ---------------- MFMA GEMM: D[row,col] = sum_k A[row,k]*B[col,k] ----------------
// R14 engine: 256 threads, 128x128 block tile, BK=64, single-buffered LDS via
// global_load_lds, 2-barrier loop with explicit vmcnt(0) drain. Kept for the
// small/odd-shaped GEMMs (steps 2, 5, 6, 7, 8a) where 32KB LDS -> 3+ blocks/CU
// occupancy beats the deep pipeline.
template <int MODE, int BIAS, bool RELU, bool STATS = false, bool COLMAX = false>
__global__ __launch_bounds__(256) void mm_k(
    const short* __restrict__ A, int lda, long long aB,
    const short* __restrict__ B, int ldb, long long bB,
    const float* __restrict__ bias, int biasStride,
    const short* __restrict__ aux, long long auxB,
    const float* __restrict__ rsv,
    float* __restrict__ Cf, long long cfB,
    short* __restrict__ Cb, long long cbB,
    float* __restrict__ Pmax, float* __restrict__ Ps2,
    int ldc, int K) {
    const int z = blockIdx.z;
    A += (long long)z * aB;
    B += (long long)z * bB;
    if (MODE == 4) { aux += (long long)z * auxB; rsv += (long long)z * GN; }
    if (MODE == 1) Cf += (long long)z * cfB;
    if (MODE == 2 || MODE == 4 || MODE == 6) Cb += (long long)z * cbB;
    if (MODE == 6) Pmax += (long long)z * GN * 32;
    const int row0 = blockIdx.x * 128, col0 = blockIdx.y * 128;
    const int tid = threadIdx.x;
    const int lane = tid & 63, w = tid >> 6;
    const int r = lane & 15, q = lane >> 4;
    const int wr = w >> 1, wc = w & 1;

    __shared__ short lA[8192];
    __shared__ short lB[8192];

    f4_t acc[4][4] = {};

    const int sRow = lane >> 2;
    const int sKb = (lane & 3) ^ ((lane >> 3) & 3);
    const long aG = (long)(row0 + w * 32 + sRow) * lda + sKb * 8;
    const long bG = (long)(col0 + w * 32 + sRow) * ldb + sKb * 8;
    short* ldsA0 = lA + (w * 32) * 32;
    short* ldsA1 = lA + (w * 32 + 16) * 32;
    short* ldsB0 = lB + (w * 32) * 32;
    short* ldsB1 = lB + (w * 32 + 16) * 32;

    const int sw = (q ^ ((r >> 1) & 3)) * 8;
    int aoff[4], boff[4];
#pragma unroll
    for (int i = 0; i < 4; ++i) {
        aoff[i] = (wr * 64 + i * 16 + r) * 32 + sw;
        boff[i] = (wc * 64 + i * 16 + r) * 32 + sw;
    }

    for (int k0 = 0; k0 < K; k0 += 64) {
        __syncthreads();
        load16_lds(A + aG + k0, ldsA0);
        load16_lds(A + aG + (long)16 * lda + k0, ldsA1);
        load16_lds(B + bG + k0, ldsB0);
        load16_lds(B + bG + (long)16 * ldb + k0, ldsB1);
        load16_lds(A + aG + k0 + 32, ldsA0 + 4096);
        load16_lds(A + aG + (long)16 * lda + k0 + 32, ldsA1 + 4096);
        load16_lds(B + bG + k0 + 32, ldsB0 + 4096);
        load16_lds(B + bG + (long)16 * ldb + k0 + 32, ldsB1 + 4096);
        asm volatile("s_waitcnt vmcnt(0)" ::: "memory");
        __syncthreads();
#pragma unroll
        for (int h = 0; h < 2; ++h) {
            const short* la = lA + h * 4096;
            const short* lb = lB + h * 4096;
            bf8_t av[4], bv[4];
#pragma unroll
            for (int i = 0; i < 4; ++i) av[i] = *(const bf8_t*)(la + aoff[i]);
#pragma unroll
            for (int j = 0; j < 4; ++j) bv[j] = *(const bf8_t*)(lb + boff[j]);
#pragma unroll
            for (int i = 0; i < 4; ++i)
#pragma unroll
                for (int j = 0; j < 4; ++j)
                    acc[i][j] = __builtin_amdgcn_mfma_f32_16x16x32_bf16(av[i], bv[j], acc[i][j], 0, 0, 0);
        }
    }

    if constexpr (MODE == 5) {
        int b = row0 >> 11;
        int rw = (blockIdx.x * 2 + wr) & 31;
#pragma unroll
        for (int j = 0; j < 4; ++j) {
            float vm = -1e30f;
#pragma unroll
            for (int i = 0; i < 4; ++i)
#pragma unroll
                for (int e = 0; e < 4; ++e) vm = fmaxf(vm, acc[i][j][e]);
            vm = fmaxf(vm, __shfl_xor(vm, 16, 64));
            vm = fmaxf(vm, __shfl_xor(vm, 32, 64));
            if (q == 0) {
                int gcol = col0 + wc * 64 + j * 16 + r;
                Pmax[(((long)b * 1024 + gcol) << 5) + rw] = vm + bias[gcol];
            }
        }
    } else if constexpr (MODE == 6) {
        float rsum[4][4] = {};
#pragma unroll
        for (int j = 0; j < 4; ++j) {
            int gcol = col0 + wc * 64 + j * 16 + r;
#pragma unroll
            for (int i = 0; i < 4; ++i) {
#pragma unroll
                for (int e = 0; e < 4; ++e) {
                    int grow = row0 + wr * 64 + i * 16 + q * 4 + e;
                    float ex = __expf(acc[i][j][e]);
                    rsum[i][e] += ex;
                    Cb[(long)grow * ldc + gcol] = f2bf(ex);
                }
            }
        }
#pragma unroll
        for (int i = 0; i < 4; ++i)
#pragma unroll
            for (int e = 0; e < 4; ++e) {
                float v = rsum[i][e];
                v += __shfl_xor(v, 1, 64);
                v += __shfl_xor(v, 2, 64);
                v += __shfl_xor(v, 4, 64);
                v += __shfl_xor(v, 8, 64);
                if (r == 0) {
                    int grow = row0 + wr * 64 + i * 16 + q * 4 + e;
                    Pmax[((long)grow << 5) + blockIdx.y * 2 + wc] = v;
                }
            }
    } else if constexpr (MODE == 4) {
#pragma unroll
        for (int i = 0; i < 4; ++i) {
#pragma unroll
            for (int e = 0; e < 4; ++e) {
                int grow = row0 + wr * 64 + i * 16 + q * 4 + e;
                float rsr = rsv[grow];
                long ob = (long)grow * ldc + col0 + wc * 64 + r;
#pragma unroll
                for (int j = 0; j < 4; ++j) {
                    long off = ob + j * 16;
                    Cb[off] = f2bf(bf2f(aux[off]) - acc[i][j][e] * rsr);
                }
            }
        }
    } else {
        const int b2d = (BIAS == 3) ? (row0 >> 11) : 0;
#pragma unroll
        for (int j = 0; j < 4; ++j) {
            int gcol = col0 + wc * 64 + j * 16 + r;
            float bvv = 0.f;
            if constexpr (BIAS == 1) bvv = bias[gcol];
            if constexpr (BIAS == 3) bvv = bias[b2d * biasStride + gcol];
            float s1 = 0.f, s2 = 0.f;
            float cmx = -1e30f;
#pragma unroll
            for (int i = 0; i < 4; ++i) {
#pragma unroll
                for (int e = 0; e < 4; ++e) {
                    int grow = row0 + wr * 64 + i * 16 + q * 4 + e;
                    float v = acc[i][j][e] + bvv;
                    if constexpr (BIAS == 2) v += bias[grow];
                    if constexpr (RELU) v = fmaxf(v, 0.f);
                    if constexpr (STATS) { s1 += v; s2 = fmaf(v, v, s2); }
                    if constexpr (COLMAX) cmx = fmaxf(cmx, v);
                    long off = (long)grow * ldc + gcol;
                    if constexpr (MODE == 1) Cf[off] = v;
                    if constexpr (MODE == 2) Cb[off] = f2bf(v);
                }
            }
            if constexpr (STATS) {
                s1 += __shfl_xor(s1, 16, 64); s1 += __shfl_xor(s1, 32, 64);
                s2 += __shfl_xor(s2, 16, 64); s2 += __shfl_xor(s2, 32, 64);
                if (q == 0) {
                    int rw2 = blockIdx.x * 2 + wr;
                    Pmax[rw2 * 512 + gcol] = s1;
                    Ps2[rw2 * 512 + gcol] = s2;
                }
            }
            if constexpr (COLMAX) {
                cmx = fmaxf(cmx, __shfl_xor(cmx, 16, 64));
                cmx = fmaxf(cmx, __shfl_xor(cmx, 32, 64));
                if (q == 0) {
                    int b = row0 >> 11;
                    int rw = (blockIdx.x * 2 + wr) & 31;
                    Pmax[(((long)b * ldc + gcol) << 5) + rw] = cmx;
                }
            }
        }
    }
}

// ================= 256x256 deep-pipelined MFMA GEMM engine (T2+T3+T4+T5) ======
// R4: relaxed barriers — ONE barrier per phase (2/tile), placed AFTER the MFMA
// cluster. No barrier between ds_read and MFMA: that dependency is per-wave
// (lgkmcnt, compiler-inserted counted waits), so wave X's MFMA now overlaps
// wave Y's ds_reads / stage-issue -> LDS pipe and matrix pipe run concurrently
// across the CU (was serialized; MfmaUtil 37%).
// WAR safety (cross-wave) with end-of-phase barriers only:
//  - phB stages A0B0(t+2) into CURRENT buf d, overwriting Ah0/Bh0 read in phA.
//    A wave reaches the end-of-phA barrier only after issuing its phA MFMAs,
//    which required its phA ds_read operands -> all waves' phA reads have
//    completed before any wave enters phB. One barrier suffices.
//  - phA stages A1B1(t+1) into buf d^1, overwriting halves last read in
//    (t-1) phB; the end-of-(t-1)phB barrier gives the same guarantee.
// Visibility: counted vmcnt(4) at phB AFTER the MFMA cluster (DMA keeps landing
// during compute), before the barrier: outstanding = A1B1(t+1)[4] + A0B0(t+2)[4]
// -> wait to 4 => tile t+1 fully landed before any wave crosses into t+1.
// Epilogue drains: t+2==NT -> vmcnt(0) once; NT==1 handled in prologue.
__device__ __forceinline__ void stage2(const short* g0, const short* g1, short* dst) {
    load16_lds(g0, dst);
    load16_lds(g1, dst + 4096);
}

template <int MH, int NH>
__device__ __forceinline__ void mfma_quad(const bf8_t (&av)[4][2], const bf8_t (&bv)[2][2],
                                          f4_t (&acc)[8][4]) {
#pragma unroll
    for (int mi = 0; mi < 4; ++mi)
#pragma unroll
        for (int ni = 0; ni < 2; ++ni) {
            acc[MH * 4 + mi][NH * 2 + ni] = __builtin_amdgcn_mfma_f32_16x16x32_bf16(
                av[mi][0], bv[ni][0], acc[MH * 4 + mi][NH * 2 + ni], 0, 0, 0);
            acc[MH * 4 + mi][NH * 2 + ni] = __builtin_amdgcn_mfma_f32_16x16x32_bf16(
                av[mi][1], bv[ni][1], acc[MH * 4 + mi][NH * 2 + ni], 0, 0, 0);
        }
}

__device__ __forceinline__ void rd4(const short* p, int swz0, int swz1, bf8_t (&v)[4][2]) {
#pragma unroll
    for (int i = 0; i < 4; ++i) {
        v[i][0] = *(const bf8_t*)(p + i * 1024 + swz0);
        v[i][1] = *(const bf8_t*)(p + i * 1024 + swz1);
    }
}
__device__ __forceinline__ void rd2(const short* p, int swz0, int swz1, bf8_t (&v)[2][2]) {
#pragma unroll
    for (int i = 0; i < 2; ++i) {
        v[i][0] = *(const bf8_t*)(p + i * 1024 + swz0);
        v[i][1] = *(const bf8_t*)(p + i * 1024 + swz1);
    }
}

#define SB0 __builtin_amdgcn_sched_barrier(0)
#define BARRIER asm volatile("s_barrier" ::: "memory")

// MODE: 2=Cb=bf16(D+bias) [opt STATS], 4=Cb=bf16(aux - rs[row]*D), 5=col-max partials
template <int MODE, int BIAS, bool RELU, bool STATS = false>
__global__ __launch_bounds__(512, 2) void mm256_k(
    const short* __restrict__ A, int lda, long long aB,
    const short* __restrict__ B, int ldb, long long bB,
    const float* __restrict__ bias, int biasStride,
    const short* __restrict__ aux, long long auxB,
    const float* __restrict__ rsv,
    short* __restrict__ Cb, long long cbB,
    float* __restrict__ Pmax, float* __restrict__ Ps2,
    int ldc, int K) {
    __shared__ short lA[32768];
    __shared__ short lB[32768];
    const int bx = blockIdx.x, by = blockIdx.y, bz = blockIdx.z;
    const int z = bz;
    A += (long long)z * aB;
    B += (long long)z * bB;
    if constexpr (MODE == 4) { aux += (long long)z * auxB; rsv += (long long)z * GN; }
    if constexpr (MODE != 5) Cb += (long long)z * cbB;
    const int row0 = bx * 256, col0 = by * 256;
    const int tid = threadIdx.x;
    const int lane = tid & 63, w = tid >> 6;
    const int r16 = lane & 15, q = lane >> 4;
    const int wr = w >> 2, wc = w & 3;

    // ---- staging sources (pre-swizzled k-slot so linear LDS dest => swizzled layout)
    const int rc0 = w * 8 + (lane >> 3);            // row-in-half, call0 (call1 = +64)
    const int s8 = ((lane & 7) ^ (rc0 & 7)) * 8;    // swizzled 16B k-slot (shorts)
    const long ldA64 = (long)64 * lda, ldB64 = (long)64 * ldb;
    const short* aH0 = A + (long)(row0 + rc0) * lda + s8;
    const short* aH1 = aH0 + (long)128 * lda;
    const short* bH0 = B + (long)(col0 + rc0) * ldb + s8;
    const short* bH1 = bH0 + (long)128 * ldb;
    short* dA = lA + w * 512;   // wave-uniform LDS chunk base (1 KB/wave/call)
    short* dB = lB + w * 512;

#define STG_A(d_, h_, kt_) stage2((h_ ? aH1 : aH0) + (long)(kt_) * 64,                      \
                                  (h_ ? aH1 : aH0) + (long)(kt_) * 64 + ldA64,              \
                                  dA + (d_) * 16384 + (h_) * 8192)
#define STG_B(d_, h_, kt_) stage2((h_ ? bH1 : bH0) + (long)(kt_) * 64,                      \
                                  (h_ ? bH1 : bH0) + (long)(kt_) * 64 + ldB64,              \
                                  dB + (d_) * 16384 + (h_) * 8192)

    // ---- fragment read offsets (swizzle XOR depends only on r16&7)
    const int swz0 = (q ^ (r16 & 7)) * 8;         // ks=0
    const int swz1 = ((4 + q) ^ (r16 & 7)) * 8;   // ks=1
    const int arow = (wr * 64 + r16) * 64;
    const int brow = (wc * 32 + r16) * 64;

    f4_t acc[8][4] = {};
    bf8_t av[4][2], bv0[2][2], bv1[2][2];
    const int NT = K >> 6;

    // ---- prologue: tile0 all 4 halves + tile1 A0B0 (if any)
    STG_A(0, 0, 0); STG_B(0, 0, 0); STG_A(0, 1, 0); STG_B(0, 1, 0);
    if (NT > 1) {
        STG_A(1, 0, 1); STG_B(1, 0, 1);
        asm volatile("s_waitcnt vmcnt(4)" ::: "memory");  // tile0 landed, tile1 A0B0 in flight
    } else {
        asm volatile("s_waitcnt vmcnt(0)" ::: "memory");
    }
    BARRIER; SB0;

    for (int t = 0; t < NT; ++t) {
        const int d = t & 1;
        const short* la = lA + d * 16384;
        const short* lb = lB + d * 16384;
        // ---- phase A: reads Ah0,Bh0,Bh1; stage A1B1(t+1); MFMA (0,0)+(0,1); barrier
        rd4(la + arow, swz0, swz1, av);
        rd2(lb + brow, swz0, swz1, bv0);
        rd2(lb + 8192 + brow, swz0, swz1, bv1);
        if (t + 1 < NT) { STG_A(d ^ 1, 1, t + 1); STG_B(d ^ 1, 1, t + 1); }
        __builtin_amdgcn_s_setprio(1);
        mfma_quad<0, 0>(av, bv0, acc);
        mfma_quad<0, 1>(av, bv1, acc);
        __builtin_amdgcn_s_setprio(0);
        BARRIER; SB0;
        // ---- phase B: reads Ah1; stage A0B0(t+2); MFMA (1,0)+(1,1); vmcnt; barrier
        rd4(la + 8192 + arow, swz0, swz1, av);
        if (t + 2 < NT) { STG_A(d, 0, t + 2); STG_B(d, 0, t + 2); }
        __builtin_amdgcn_s_setprio(1);
        mfma_quad<1, 0>(av, bv0, acc);
        mfma_quad<1, 1>(av, bv1, acc);
        __builtin_amdgcn_s_setprio(0);
        if (t + 2 < NT) {
            asm volatile("s_waitcnt vmcnt(4)" ::: "memory");  // tile t+1 fully landed
        } else if (t + 1 < NT) {
            asm volatile("s_waitcnt vmcnt(0)" ::: "memory");  // drain for final tile
        }
        BARRIER; SB0;
    }
#undef STG_A
#undef STG_B

    // ---- epilogues ----
    const int mrow = row0 + wr * 64 + q * 4;   // + mh*128 + mi*16 + e
    const int ncol = col0 + wc * 32 + r16;     // + nh*128 + ni*16

    if constexpr (MODE == 4) {
#pragma unroll
        for (int m = 0; m < 8; ++m) {
#pragma unroll
            for (int e = 0; e < 4; ++e) {
                const int grow = mrow + (m >> 2) * 128 + (m & 3) * 16 + e;
                const float rsr = rsv[grow];
                const long rb = (long)grow * ldc;
#pragma unroll
                for (int n = 0; n < 4; ++n) {
                    const long off = rb + ncol + (n >> 1) * 128 + (n & 1) * 16;
                    Cb[off] = f2bf(bf2f(aux[off]) - acc[m][n][e] * rsr);
                }
            }
        }
    } else if constexpr (MODE == 2) {
        const int b2d = (BIAS == 3) ? (row0 >> 11) : 0;
#pragma unroll
        for (int n = 0; n < 4; ++n) {
            const int gcol = ncol + (n >> 1) * 128 + (n & 1) * 16;
            float bvv = 0.f;
            if constexpr (BIAS == 1) bvv = bias[gcol];
            if constexpr (BIAS == 3) bvv = bias[b2d * biasStride + gcol];
#pragma unroll
            for (int mh = 0; mh < 2; ++mh) {
                float s1 = 0.f, s2 = 0.f;
#pragma unroll
                for (int mi = 0; mi < 4; ++mi) {
#pragma unroll
                    for (int e = 0; e < 4; ++e) {
                        const int grow = mrow + mh * 128 + mi * 16 + e;
                        float v = acc[mh * 4 + mi][n][e] + bvv;
                        if constexpr (BIAS == 2) v += bias[grow];
                        if constexpr (RELU) v = fmaxf(v, 0.f);
                        if constexpr (STATS) { s1 += v; s2 = fmaf(v, v, s2); }
                        Cb[(long)grow * ldc + gcol] = f2bf(v);
                    }
                }
                if constexpr (STATS) {
                    s1 += __shfl_xor(s1, 16, 64); s1 += __shfl_xor(s1, 32, 64);
                    s2 += __shfl_xor(s2, 16, 64); s2 += __shfl_xor(s2, 32, 64);
                    if (q == 0) {
                        const int rw2 = bx * 4 + mh * 2 + wr;  // 64-row group
                        Pmax[rw2 * 512 + gcol] = s1;
                        Ps2[rw2 * 512 + gcol] = s2;
                    }
                }
            }
        }
    } else if constexpr (MODE == 5) {
        const int b = row0 >> 11;
#pragma unroll
        for (int n = 0; n < 4; ++n) {
            const int gcol = ncol + (n >> 1) * 128 + (n & 1) * 16;
            const float bvv = bias[gcol];
#pragma unroll
            for (int mh = 0; mh < 2; ++mh) {
                float vm = -1e30f;
#pragma unroll
                for (int mi = 0; mi < 4; ++mi)
#pragma unroll
                    for (int e = 0; e < 4; ++e) vm = fmaxf(vm, acc[mh * 4 + mi][n][e]);
                vm = fmaxf(vm, __shfl_xor(vm, 16, 64));
                vm = fmaxf(vm, __shfl_xor(vm, 32, 64));
                if (q == 0) {
                    const int rw = (bx * 4 + mh * 2 + wr) & 31;
                    Pmax[(((long)b * ldc + gcol) << 5) + rw] = vm + bvv;
                }
            }
        }
    }
}
#undef SB0
#undef BARRIER

// ---------------- rs[q] = 1 / sum of 32 row partials ----------------
__global__ __launch_bounds__(256) void rs_k(const float* __restrict__ rp,
                                            float* __restrict__ rs) {
    int i = blockIdx.x * 256 + threadIdx.x;
    const float* p = rp + ((long)i << 5);
    float s = 0.f;
#pragma unroll
    for (int j = 0; j < 32; ++j) s += p[j];
    rs[i] = 1.f / s;
}

// ---------------- g[i] = max over 32 partials ----------------
__global__ __launch_bounds__(256) void maxg_k(const float* __restrict__ P,
                                              float* __restrict__ g) {
    int i = blockIdx.x * 256 + threadIdx.x;
    const float* p = P + ((long)i << 5);
    float m = p[0];
#pragma unroll
    for (int j = 1; j < 32; ++j) m = fmaxf(m, p[j]);
    g[i] = m;
}

// ---------------- cvec[b,o] = b3[o] + sum_c w3[o,256+c]*g[b,c] (fp32) ----------------
__global__ __launch_bounds__(256) void cvec_k(const float* __restrict__ w3,
                                              const float* __restrict__ b3,
                                              const float* __restrict__ g,
                                              float* __restrict__ cvec) {
    int idx = blockIdx.x * 256 + threadIdx.x;
    int b = idx >> 9, o = idx & 511;
    const float* gb = g + (b << 8);
    const float* wr = w3 + (long)o * 512 + 256;
    float s = b3[o];
    for (int c = 0; c < 256; ++c) s = fmaf(wr[c], gb[c], s);
    cvec[idx] = s;
}

// ---------------- column sums of attn = P * rs[q] over q (two-stage) ----------------
// vectorized: 16B/lane coalesced reads, 8 columns per thread
__global__ __launch_bounds__(256) void colsum1_k(const short* __restrict__ Ab,
                                                 const float* __restrict__ rs,
                                                 float* __restrict__ cp) {
    const int qs = blockIdx.x, z = blockIdx.y;
    const int k0 = threadIdx.x * 8;
    const short* p = Ab + (long)z * GN * GN + (long)qs * 64 * GN + k0;
    const float* rv = rs + z * GN + qs * 64;
    float s[8] = {};
    for (int qq = 0; qq < 64; ++qq) {
        uint4 v = *(const uint4*)(p + (long)qq * GN);
        const float rr = rv[qq];
        const short* sp = (const short*)&v;
#pragma unroll
        for (int j = 0; j < 8; ++j) s[j] = fmaf(bf2f(sp[j]), rr, s[j]);
    }
    float* o = cp + ((long)(z * 32 + qs) * GN) + k0;
#pragma unroll
    for (int j = 0; j < 8; ++j) o[j] = s[j];
}
__global__ __launch_bounds__(256) void colsum2_k(const float* __restrict__ cp,
                                                 float* __restrict__ cs) {
    int k = blockIdx.x * 256 + threadIdx.x, z = blockIdx.y;
    float s = 1e-9f;
    for (int qs = 0; qs < 32; ++qs) s += cp[((z * 32 + qs) * GN) + k];
    cs[z * GN + k] = s;
}

// ---------------- xvc[c,p] /= cs[p]  (in place) ----------------
__global__ __launch_bounds__(256) void xvscale_k(short* __restrict__ xvc,
                                                 const float* __restrict__ cs) {
    long idx = ((long)blockIdx.x * 256 + threadIdx.x) * 4;
    int p = (int)(idx & 32767);
    short* ptr = xvc + idx;
    float4 cv = *(const float4*)(cs + p);
    uint2 u = *(const uint2*)ptr;
    short* sp = (short*)&u;
    sp[0] = f2bf(bf2f(sp[0]) / cv.x);
    sp[1] = f2bf(bf2f(sp[1]) / cv.y);
    sp[2] = f2bf(bf2f(sp[2]) / cv.z);
    sp[3] = f2bf(bf2f(sp[3]) / cv.w);
    *(uint2*)ptr = u;
}

// ---------------- BN scale/shift from fused GEMM stats [512][512] ----------------
__global__ __launch_bounds__(256) void bn2_k(const float* __restrict__ bs1,
                                             const float* __restrict__ bs2,
                                             const float* __restrict__ gamma,
                                             const float* __restrict__ beta,
                                             float* __restrict__ sc,
                                             float* __restrict__ sh) {
    int c = blockIdx.x;
    float s = 0.f, s2 = 0.f;
    for (int i = threadIdx.x; i < 512; i += 256) {
        s += bs1[i * 512 + c];
        s2 += bs2[i * 512 + c];
    }
    s = block_sum(s);
    s2 = block_sum(s2);
    if (threadIdx.x == 0) {
        const float cnt = (float)(GB * GN);
        float mu = s / cnt;
        float var = s2 / cnt - mu * mu;
        float r = rsqrtf(var + 1e-5f);
        float gm = gamma[c] * r;
        sc[c] = gm;
        sh[c] = beta[c] - gm * mu;
    }
}

// ---------------- h4T = bf16(h3b + relu(d*sc+sh)) ----------------
__global__ __launch_bounds__(256) void bn_apply_k(const short* __restrict__ h3b,
                                                  const short* __restrict__ d,
                                                  const float* __restrict__ sc,
                                                  const float* __restrict__ sh,
                                                  short* __restrict__ h4) {
    long bidx = ((long)blockIdx.x * 256 + threadIdx.x) * 4;
    int c = (int)(bidx & 511);
    uint2 du = *(const uint2*)(d + bidx);
    short* ds = (short*)&du;
    uint2 hu = *(const uint2*)(h3b + bidx);
    short* hs = (short*)&hu;
    float4 a4 = *(const float4*)(sc + c);
    float4 b4 = *(const float4*)(sh + c);
    float r0 = bf2f(hs[0]) + fmaxf(fmaf(bf2f(ds[0]), a4.x, b4.x), 0.f);
    float r1 = bf2f(hs[1]) + fmaxf(fmaf(bf2f(ds[1]), a4.y, b4.y), 0.f);
    float r2 = bf2f(hs[2]) + fmaxf(fmaf(bf2f(ds[2]), a4.z, b4.z), 0.f);
    float r3 = bf2f(hs[3]) + fmaxf(fmaf(bf2f(ds[3]), a4.w, b4.w), 0.f);
    uint2 o;
    o.x = (unsigned short)f2bf(r0) | ((unsigned)(unsigned short)f2bf(r1) << 16);
    o.y = (unsigned short)f2bf(r2) | ((unsigned)(unsigned short)f2bf(r3) << 16);
    *(uint2*)(h4 + bidx) = o;
}

// ---------------- out[i] = max over 32 partials ----------------
__global__ __launch_bounds__(256) void max_final_k(const float* __restrict__ P,
                                                   float* __restrict__ out) {
    int i = blockIdx.x * 256 + threadIdx.x;
    const float* p = P + ((long)i << 5);
    float m = p[0];
#pragma unroll
    for (int j = 1; j < 32; ++j) m = fmaxf(m, p[j]);
    out[i] = m;
}

extern "C" void kernel_launch(void* const* d_in, const int* in_sizes, int n_in,
                              void* d_out, int out_size, void* d_ws, size_t ws_size,
                              hipStream_t stream) {
    const float* x = (const float*)d_in[0];
    const float* w1 = (const float*)d_in[1];
    const float* b1 = (const float*)d_in[2];
    const float* w2 = (const float*)d_in[3];
    const float* b2 = (const float*)d_in[4];
    const float* w3 = (const float*)d_in[5];
    const float* b3 = (const float*)d_in[6];
    const float* w4 = (const float*)d_in[7];
    const float* b4 = (const float*)d_in[8];
    const float* wqk = (const float*)d_in[9];
    const float* wv = (const float*)d_in[10];
    const float* bv = (const float*)d_in[11];
    const float* wt = (const float*)d_in[12];
    const float* bt = (const float*)d_in[13];
    const float* gamma = (const float*)d_in[14];
    const float* beta = (const float*)d_in[15];
    float* out = (float*)d_out;

    // ---- workspace carve (bytes), peak ~255.05 MB (unchanged) ----
    char* base = (char*)d_ws;
    short* h3b = (short*)base;                    // [32768,512] bf16 32 MB
    short* hsT = (short*)(base + 33554432);       // [32768,512] bf16 32 MB
    short* kT  = (short*)(base + 67108864);       // [32768,128] bf16  8 MB
    short* xvc = (short*)(base + 75497472);       // [512,32768] bf16 32 MB (channel-major)
    short* EA  = (short*)(base + 109051904);      // [16,2048,2048] bf16 128 MB (P = exp(E))
    short* h1T = (short*)(base + 109051904);      //   alias (early, dead before EA)
    short* h2T = (short*)(base + 117440512);      //   alias (early)
    short* dTb = (short*)(base + 109051904);      //   alias [32768,512] bf16 (late, EA dead)
    short* h4T = (short*)(base + 67108864);       //   alias 32 MB over kT+xvc (late)
    char* S = base + 243269632;
    float* g    = (float*)(S + 262144);           // 16384
    float* cvec = (float*)(S + 278528);           // 32768
    float* cp   = (float*)(S + 311296);           // 4 MB [16,32,2048]; rp aliases (earlier)
    float* rp   = cp;                             //   [32768,32] row-sum partials
    float* cs   = (float*)(S + 4505600);          // 128 KB [16,2048]
    float* bs1  = (float*)(S + 4636672);          // 1 MB [512,512] fused BN sum partials
    float* bs2  = (float*)(S + 5685248);          // 1 MB [512,512] fused BN sumsq partials
    float* bnsc = (float*)(S + 6733824);          // 2048
    float* bnsh = (float*)(S + 6735872);          // 2048
    float* Pmax = (float*)(S + 6737920);          // 2 MB partials
    short* w2b  = (short*)(S + 8835072);          // bf16 weights, CONTIGUOUS region
    short* w3b  = (short*)(S + 8900608);
    short* wqkb = (short*)(S + 9424896);
    short* wvb  = (short*)(S + 9555968);
    short* wtb  = (short*)(S + 10080256);
    short* w4b  = (short*)(S + 10604544);
    float* rs   = (float*)(S + 11653120);         // 128 KB [16,2048] 1/rowsum

    // 0. all weight converts in one kernel
    f2ball_k<<<5505, 256, 0, stream>>>(w2, w3, wqk, wv, wt, w4, w2b);

    // 1. posenc + conv1 + relu -> h1T
    posenc_conv1_k<<<128, 256, 0, stream>>>(x, w1, b1, h1T);

    // 2. h2T = h1T @ w2^T + b2 + fused per-batch col-max partials (old engine)
    mm_k<2, 1, false, false, true><<<dim3(256, 2, 1), 256, 0, stream>>>(
        h1T, 128, 0, w2b, 128, 0, b2, 0, nullptr, 0, nullptr,
        nullptr, 0, h2T, 0, Pmax, nullptr, 256, 128);

    // 3. g[b,c] = max over 32 partials
    maxg_k<<<16, 256, 0, stream>>>(Pmax, g);

    // 4. cvec = w3[:,256:] @ g + b3 (fp32)
    cvec_k<<<32, 256, 0, stream>>>(w3, b3, g, cvec);

    // 5. h3b = bf16(relu(h2T @ w3[:,:256]^T + cvec))  [old engine — 3 blocks/CU wins at K=256]
    mm_k<2, 3, true><<<dim3(256, 4, 1), 256, 0, stream>>>(
        h2T, 256, 0, w3b, 512, 0, cvec, 512, nullptr, 0, nullptr,
        nullptr, 0, h3b, 0, nullptr, nullptr, 512, 256);

    // 6. kT = h3b @ wqk^T (cols=128 < 256: old engine)
    mm_k<2, 0, false><<<dim3(256, 1, 1), 256, 0, stream>>>(
        h3b, 512, 0, wqkb, 512, 0, nullptr, 0, nullptr, 0, nullptr,
        nullptr, 0, kT, 0, nullptr, nullptr, 128, 512);

    // 7. xv channel-major: D[c, point] = wv @ h3 + bv(row)  [old engine]
    mm_k<2, 2, false><<<dim3(4, 256, 1), 256, 0, stream>>>(
        wvb, 512, 0, h3b, 512, 0, bv, 0, nullptr, 0, nullptr,
        nullptr, 0, xvc, 0, nullptr, nullptr, 32768, 512);

    // 8a. P = exp(kT kT^T) bf16 + row-sum partials rp (old engine)
    mm_k<6, 0, false><<<dim3(16, 16, 16), 256, 0, stream>>>(
        kT, 128, (long long)GN * 128, kT, 128, (long long)GN * 128,
        nullptr, 0, nullptr, 0, nullptr, nullptr, 0,
        EA, (long long)GN * GN, rp, nullptr, GN, 128);
    // 8b. rs = 1/rowsum
    rs_k<<<128, 256, 0, stream>>>(rp, rs);
    // 8c. column sums of attn = P*rs (vectorized)
    colsum1_k<<<dim3(32, GB), 256, 0, stream>>>(EA, rs, cp);
    colsum2_k<<<dim3(8, GB), 256, 0, stream>>>(cp, cs);
    // 8d. fold L1 renorm into xv (in place)
    xvscale_k<<<16384, 256, 0, stream>>>(xvc, cs);
    // 8e. hsT = bf16(h3b - rs[q] * (P @ xv'^T))  [relaxed-barrier engine]
    mm256_k<4, 0, false><<<dim3(8, 2, 16), 512, 0, stream>>>(
        EA, GN, (long long)GN * GN,
        xvc, 32768, (long long)GN,
        nullptr, 0, h3b, (long long)GN * 512, rs,
        hsT, (long long)GN * 512, nullptr, nullptr, 512, GN);

    // 9. dTb = bf16(hsT @ wt^T + bt) + fused BN stat partials  [relaxed-barrier engine]
    mm256_k<2, 1, false, true><<<dim3(128, 2, 1), 512, 0, stream>>>(
        hsT, 512, 0, wtb, 512, 0, bt, 0, nullptr, 0, nullptr,
        dTb, 0, bs1, bs2, 512, 512);

    // 10. BN scale/shift from fused stats
    bn2_k<<<512, 256, 0, stream>>>(bs1, bs2, gamma, beta, bnsc, bnsh);

    // 11. h4T = bf16(h3b + relu(bn(dTb)))
    bn_apply_k<<<16384, 256, 0, stream>>>(h3b, dTb, bnsc, bnsh, h4T);

    // 12. fused final conv + per-wave-tile col max -> Pmax [16,1024,32]  [relaxed-barrier engine]
    mm256_k<5, 1, false><<<dim3(128, 4, 1), 512, 0, stream>>>(
        h4T, 512, 0, w4b, 512, 0, b4, 0, nullptr, 0, nullptr,
        nullptr, 0, Pmax, nullptr, 1024, 512);

    // 13. out = max over tiles
    max_final_k<<<64, 256, 0, stream>>>(Pmax, out);
}